// Round 2
// baseline (1207.296 us; speedup 1.0000x reference)
//
#include <hip/hip_runtime.h>

// ---------------------------------------------------------------------------
// Hetero 2-layer GraphSAGE — CSR-gather formulation (no f32 atomics).
//
// Pipeline:
//   1. CSR build for all 4 relations (keyed by dst):
//      memset counters -> histogram (int atomics) -> single global exclusive
//      scan over concatenated counters [wr|rv|wb|rb] -> cursor fill.
//      row_ptr diffs give neighbor counts for free; CSR reused by BOTH layers.
//   2. Pretransform (one thread per node): h_rel = x @ W_l(rel) for the two
//      out-relations, root = x @ (W_r(a)+W_r(b)).  64->16, weights in LDS.
//   3. L1 fused gather: per dst node, register-accumulate neighbor h rows via
//      CSR, scale by 1/max(deg,1), + root + biases, relu -> t1/d1.
//   4. L2 fused gather+matmul: gather 16-dim means into LDS, then in-block
//      16->32 matmul (weights in LDS) -> d_out directly.
//
// Workspace: ints [cnt 1.2M | rp 1.2M+1 | cursor 1.2M | eidx 4M] then floats
// [h_wr 1.6M | h_rv 1.6M | h_wb 8M | h_rb 8M | root_d 1.6M | root_t 8M |
//  t1 8M | d1 1.6M]  ~= 184 MB total.
// ---------------------------------------------------------------------------

#define N_DEV   100000
#define N_TASK  500000
#define NEDGE   1000000
#define NCNT    1200000          // 500K (wr) + 500K (rv) + 100K (wb) + 100K (rb)
#define BASE_WR 0
#define BASE_RV 500000
#define BASE_WB 1000000
#define BASE_RB 1100000

#define SCAN_PER   16
#define SCAN_CHUNK 4096          // 256 threads * 16
#define SCAN_NBLK  293           // ceil(1.2M / 4096)

struct EdgePtrs {
    const int* src0; const int* dst0;
    const int* src1; const int* dst1;
    const int* src2; const int* dst2;
    const int* src3; const int* dst3;
};

// ---- CSR step 1: histogram over 4 relations (blockIdx.y = relation) ----
__global__ __launch_bounds__(256) void hist4(EdgePtrs ep, int* __restrict__ cnt)
{
    const int e = blockIdx.x * 256 + threadIdx.x;
    if (e >= NEDGE) return;
    const int y = blockIdx.y;
    const int* dst = y == 0 ? ep.dst0 : y == 1 ? ep.dst1 : y == 2 ? ep.dst2 : ep.dst3;
    const int base = y == 0 ? BASE_WR : y == 1 ? BASE_RV : y == 2 ? BASE_WB : BASE_RB;
    atomicAdd(&cnt[base + dst[e]], 1);
}

// ---- CSR step 2a: per-block sums of counters ----
__global__ __launch_bounds__(256) void scan_block_sums(
    const int* __restrict__ c, int* __restrict__ bsum)
{
    __shared__ int sm[256];
    const int t = threadIdx.x;
    const int base = blockIdx.x * SCAN_CHUNK + t * SCAN_PER;
    int s = 0;
#pragma unroll
    for (int k = 0; k < SCAN_PER; k += 4) {
        const int idx = base + k;
        if (idx + 3 < NCNT) {
            const int4 v = *reinterpret_cast<const int4*>(&c[idx]);
            s += v.x + v.y + v.z + v.w;
        } else {
            for (int q = 0; q < 4; ++q) if (idx + q < NCNT) s += c[idx + q];
        }
    }
    sm[t] = s;
    __syncthreads();
    for (int off = 128; off > 0; off >>= 1) {
        if (t < off) sm[t] += sm[t + off];
        __syncthreads();
    }
    if (t == 0) bsum[blockIdx.x] = sm[0];
}

// ---- CSR step 2b: exclusive scan of block sums (single block) ----
__global__ __launch_bounds__(512) void scan_bsum(int* __restrict__ bsum)
{
    __shared__ int sm[512];
    const int t = threadIdx.x;
    const int own = (t < SCAN_NBLK) ? bsum[t] : 0;
    sm[t] = own;
    __syncthreads();
    for (int off = 1; off < 512; off <<= 1) {
        int v = sm[t];
        if (t >= off) v += sm[t - off];
        __syncthreads();
        sm[t] = v;
        __syncthreads();
    }
    if (t < SCAN_NBLK) bsum[t] = sm[t] - own;   // exclusive
}

// ---- CSR step 2c: final exclusive scan -> row_ptr ----
__global__ __launch_bounds__(256) void scan_final(
    const int* __restrict__ c, const int* __restrict__ bsum, int* __restrict__ rp)
{
    __shared__ int sm[256];
    const int t = threadIdx.x;
    const int base = blockIdx.x * SCAN_CHUNK + t * SCAN_PER;
    int vals[SCAN_PER];
    int s = 0;
#pragma unroll
    for (int k = 0; k < SCAN_PER; k += 4) {
        const int idx = base + k;
        int4 v = make_int4(0, 0, 0, 0);
        if (idx + 3 < NCNT) {
            v = *reinterpret_cast<const int4*>(&c[idx]);
        } else {
            if (idx + 0 < NCNT) v.x = c[idx + 0];
            if (idx + 1 < NCNT) v.y = c[idx + 1];
            if (idx + 2 < NCNT) v.z = c[idx + 2];
            if (idx + 3 < NCNT) v.w = c[idx + 3];
        }
        vals[k + 0] = v.x; vals[k + 1] = v.y; vals[k + 2] = v.z; vals[k + 3] = v.w;
        s += v.x + v.y + v.z + v.w;
    }
    const int own = s;
    sm[t] = own;
    __syncthreads();
    for (int off = 1; off < 256; off <<= 1) {
        int v = sm[t];
        if (t >= off) v += sm[t - off];
        __syncthreads();
        sm[t] = v;
        __syncthreads();
    }
    int run = sm[t] - own + bsum[blockIdx.x];
#pragma unroll
    for (int k = 0; k < SCAN_PER; ++k) {
        if (base + k < NCNT) rp[base + k] = run;
        run += vals[k];
    }
    if (blockIdx.x == 0 && t == 0) rp[NCNT] = 4 * NEDGE;
}

// ---- CSR step 3: fill edge index array via cursors ----
__global__ __launch_bounds__(256) void fill4(
    EdgePtrs ep, int* __restrict__ cursor, int* __restrict__ eidx)
{
    const int e = blockIdx.x * 256 + threadIdx.x;
    if (e >= NEDGE) return;
    const int y = blockIdx.y;
    const int* src = y == 0 ? ep.src0 : y == 1 ? ep.src1 : y == 2 ? ep.src2 : ep.src3;
    const int* dst = y == 0 ? ep.dst0 : y == 1 ? ep.dst1 : y == 2 ? ep.dst2 : ep.dst3;
    const int base = y == 0 ? BASE_WR : y == 1 ? BASE_RV : y == 2 ? BASE_WB : BASE_RB;
    const int pos = atomicAdd(&cursor[base + dst[e]], 1);
    eidx[pos] = src[e];
}

// ---- pretransform: one thread per node. outA=x@WA, outB=x@WB, outC=x@(WC1+WC2)
__global__ __launch_bounds__(256) void pretransform3(
    const float* __restrict__ x,
    const float* __restrict__ WA, const float* __restrict__ WB,
    const float* __restrict__ WC1, const float* __restrict__ WC2,
    float* __restrict__ outA, float* __restrict__ outB, float* __restrict__ outC,
    int n)
{
    __shared__ float wA[64 * 16], wB[64 * 16], wC[64 * 16];
    const int t = threadIdx.x;
    for (int i = t; i < 64 * 16; i += 256) {
        wA[i] = WA[i];
        wB[i] = WB[i];
        wC[i] = WC1[i] + WC2[i];
    }
    __syncthreads();

    const int node = blockIdx.x * 256 + t;
    if (node >= n) return;

    float a[16], b[16], c[16];
#pragma unroll
    for (int i = 0; i < 16; ++i) { a[i] = 0.f; b[i] = 0.f; c[i] = 0.f; }

    const float4* xr = reinterpret_cast<const float4*>(&x[(size_t)node * 64]);
    for (int k4 = 0; k4 < 16; ++k4) {
        const float4 xv = xr[k4];
#pragma unroll
        for (int q = 0; q < 4; ++q) {
            const int k = k4 * 4 + q;
            const float xq = (q == 0) ? xv.x : (q == 1) ? xv.y : (q == 2) ? xv.z : xv.w;
#pragma unroll
            for (int cix = 0; cix < 16; ++cix) {
                a[cix] = fmaf(xq, wA[k * 16 + cix], a[cix]);
                b[cix] = fmaf(xq, wB[k * 16 + cix], b[cix]);
                c[cix] = fmaf(xq, wC[k * 16 + cix], c[cix]);
            }
        }
    }
    float4* oA = reinterpret_cast<float4*>(&outA[(size_t)node * 16]);
    float4* oB = reinterpret_cast<float4*>(&outB[(size_t)node * 16]);
    float4* oC = reinterpret_cast<float4*>(&outC[(size_t)node * 16]);
#pragma unroll
    for (int i = 0; i < 4; ++i) {
        oA[i] = make_float4(a[i*4], a[i*4+1], a[i*4+2], a[i*4+3]);
        oB[i] = make_float4(b[i*4], b[i*4+1], b[i*4+2], b[i*4+3]);
        oC[i] = make_float4(c[i*4], c[i*4+1], c[i*4+2], c[i*4+3]);
    }
}

// ---- L1 fused gather: out = relu(mean_A + mean_B + root + bA + bB), 16 lanes/node
__global__ __launch_bounds__(256) void gather_l1(
    const float* __restrict__ hA, const float* __restrict__ hB,
    const int* __restrict__ rp, const int* __restrict__ eidx,
    int baseA, int baseB,
    const float* __restrict__ root,
    const float* __restrict__ bA, const float* __restrict__ bB,
    float* __restrict__ out, int n)
{
    const int t = blockIdx.x * 256 + threadIdx.x;
    const int i = t >> 4;
    const int j = t & 15;
    if (i >= n) return;

    const int a0 = rp[baseA + i], a1 = rp[baseA + i + 1];
    const int b0 = rp[baseB + i], b1 = rp[baseB + i + 1];

    float accA = 0.f, accB = 0.f;
    int e = a0;
    for (; e + 1 < a1; e += 2) {
        const int s0 = eidx[e], s1 = eidx[e + 1];
        accA += hA[(size_t)s0 * 16 + j];
        accA += hA[(size_t)s1 * 16 + j];
    }
    if (e < a1) accA += hA[(size_t)eidx[e] * 16 + j];
    e = b0;
    for (; e + 1 < b1; e += 2) {
        const int s0 = eidx[e], s1 = eidx[e + 1];
        accB += hB[(size_t)s0 * 16 + j];
        accB += hB[(size_t)s1 * 16 + j];
    }
    if (e < b1) accB += hB[(size_t)eidx[e] * 16 + j];

    const float invA = 1.f / fmaxf((float)(a1 - a0), 1.f);
    const float invB = 1.f / fmaxf((float)(b1 - b0), 1.f);
    const float v = accA * invA + accB * invB + root[(size_t)i * 16 + j] + bA[j] + bB[j];
    out[(size_t)i * 16 + j] = fmaxf(v, 0.f);
}

// ---- L2 fused gather + 16->32 matmul. 16 nodes/block, 16 lanes/node ----
__global__ __launch_bounds__(256) void gather_l2(
    const float* __restrict__ hA, const float* __restrict__ hB,
    const int* __restrict__ rp, const int* __restrict__ eidx,
    int baseA, int baseB,
    const float* __restrict__ xroot,
    const float* __restrict__ WA, const float* __restrict__ WB,
    const float* __restrict__ WR1, const float* __restrict__ WR2,
    const float* __restrict__ bA, const float* __restrict__ bB,
    float* __restrict__ out, int n)
{
    __shared__ float wA[512], wB[512], wR[512], bs[32];
    __shared__ float smA[16][17], smB[16][17], smR[16][17];

    const int t = threadIdx.x;
    for (int i = t; i < 512; i += 256) {
        wA[i] = WA[i];
        wB[i] = WB[i];
        wR[i] = WR1[i] + WR2[i];
    }
    if (t < 32) bs[t] = bA[t] + bB[t];

    const int g = t >> 4;
    const int j = t & 15;
    const int i = blockIdx.x * 16 + g;

    float mA = 0.f, mB = 0.f, r = 0.f;
    if (i < n) {
        const int a0 = rp[baseA + i], a1 = rp[baseA + i + 1];
        const int b0 = rp[baseB + i], b1 = rp[baseB + i + 1];
        int e = a0;
        for (; e + 1 < a1; e += 2) {
            const int s0 = eidx[e], s1 = eidx[e + 1];
            mA += hA[(size_t)s0 * 16 + j];
            mA += hA[(size_t)s1 * 16 + j];
        }
        if (e < a1) mA += hA[(size_t)eidx[e] * 16 + j];
        e = b0;
        for (; e + 1 < b1; e += 2) {
            const int s0 = eidx[e], s1 = eidx[e + 1];
            mB += hB[(size_t)s0 * 16 + j];
            mB += hB[(size_t)s1 * 16 + j];
        }
        if (e < b1) mB += hB[(size_t)eidx[e] * 16 + j];
        mA *= 1.f / fmaxf((float)(a1 - a0), 1.f);
        mB *= 1.f / fmaxf((float)(b1 - b0), 1.f);
        r = xroot[(size_t)i * 16 + j];
    }
    smA[g][j] = mA;
    smB[g][j] = mB;
    smR[g][j] = r;
    __syncthreads();

    // phase 2: same thread -> node g, cols j and j+16
    if (i >= n) return;
    float acc0 = bs[j], acc1 = bs[j + 16];
#pragma unroll
    for (int k = 0; k < 16; ++k) {
        const float a = smA[g][k], b = smB[g][k], rr = smR[g][k];
        acc0 = fmaf(a,  wA[k * 32 + j],      acc0);
        acc1 = fmaf(a,  wA[k * 32 + j + 16], acc1);
        acc0 = fmaf(b,  wB[k * 32 + j],      acc0);
        acc1 = fmaf(b,  wB[k * 32 + j + 16], acc1);
        acc0 = fmaf(rr, wR[k * 32 + j],      acc0);
        acc1 = fmaf(rr, wR[k * 32 + j + 16], acc1);
    }
    out[(size_t)i * 32 + j]      = acc0;
    out[(size_t)i * 32 + j + 16] = acc1;
}

extern "C" void kernel_launch(void* const* d_in, const int* in_sizes, int n_in,
                              void* d_out, int out_size, void* d_ws, size_t ws_size,
                              hipStream_t stream)
{
    const float* x_dev  = (const float*)d_in[0];
    const float* x_task = (const float*)d_in[1];
    const int* wr_src = (const int*)d_in[2];
    const int* wr_dst = (const int*)d_in[3];
    const int* rv_src = (const int*)d_in[4];
    const int* rv_dst = (const int*)d_in[5];
    const int* wb_src = (const int*)d_in[6];
    const int* wb_dst = (const int*)d_in[7];
    const int* rb_src = (const int*)d_in[8];
    const int* rb_dst = (const int*)d_in[9];
    const float* p1wr_wl = (const float*)d_in[10];
    const float* p1wr_bl = (const float*)d_in[11];
    const float* p1wr_wr = (const float*)d_in[12];
    const float* p1rv_wl = (const float*)d_in[13];
    const float* p1rv_bl = (const float*)d_in[14];
    const float* p1rv_wr = (const float*)d_in[15];
    const float* p1wb_wl = (const float*)d_in[16];
    const float* p1wb_bl = (const float*)d_in[17];
    const float* p1wb_wr = (const float*)d_in[18];
    const float* p1rb_wl = (const float*)d_in[19];
    const float* p1rb_bl = (const float*)d_in[20];
    const float* p1rb_wr = (const float*)d_in[21];
    const float* p2wr_wl = (const float*)d_in[22];
    const float* p2wr_bl = (const float*)d_in[23];
    const float* p2wr_wr = (const float*)d_in[24];
    const float* p2rv_wl = (const float*)d_in[25];
    const float* p2rv_bl = (const float*)d_in[26];
    const float* p2rv_wr = (const float*)d_in[27];
    const float* p2wb_wl = (const float*)d_in[28];
    const float* p2wb_bl = (const float*)d_in[29];
    const float* p2wb_wr = (const float*)d_in[30];
    const float* p2rb_wl = (const float*)d_in[31];
    const float* p2rb_bl = (const float*)d_in[32];
    const float* p2rb_wr = (const float*)d_in[33];

    // ---- workspace carve-up ----
    int* wsI = (int*)d_ws;
    int* cnt    = wsI + 0;          // 1.2M
    int* rp     = wsI + 1200000;    // 1.2M + 1
    int* cursor = wsI + 2400004;    // 1.2M
    int* eidx   = wsI + 3600004;    // 4M
    int* bsum   = wsI + 7600004;    // 512 (scan block sums)
    float* wsF = (float*)d_ws + 7700000;   // float region, 16B aligned
    float* h_wr   = wsF + 0;         // dev  x16
    float* h_rv   = wsF + 1600000;   // dev  x16
    float* h_wb   = wsF + 3200000;   // task x16
    float* h_rb   = wsF + 11200000;  // task x16
    float* root_d = wsF + 19200000;  // dev  x16
    float* root_t = wsF + 20800000;  // task x16
    float* t1     = wsF + 28800000;  // task x16
    float* d1     = wsF + 36800000;  // dev  x16

    float* out = (float*)d_out;      // [d2: 100K x32 | t2: 500K x32]

    EdgePtrs ep;
    ep.src0 = wr_src; ep.dst0 = wr_dst;
    ep.src1 = rv_src; ep.dst1 = rv_dst;
    ep.src2 = wb_src; ep.dst2 = wb_dst;
    ep.src3 = rb_src; ep.dst3 = rb_dst;

    const dim3 egrid((NEDGE + 255) / 256, 4);

    // ---- 1. CSR build ----
    hipMemsetAsync(cnt, 0, (size_t)NCNT * sizeof(int), stream);
    hist4<<<egrid, 256, 0, stream>>>(ep, cnt);
    scan_block_sums<<<SCAN_NBLK, 256, 0, stream>>>(cnt, bsum);
    scan_bsum<<<1, 512, 0, stream>>>(bsum);
    scan_final<<<SCAN_NBLK, 256, 0, stream>>>(cnt, bsum, rp);
    hipMemcpyAsync(cursor, rp, (size_t)NCNT * sizeof(int),
                   hipMemcpyDeviceToDevice, stream);
    fill4<<<egrid, 256, 0, stream>>>(ep, cursor, eidx);

    // ---- 2. pretransforms (h_rel + summed-root) ----
    pretransform3<<<(N_DEV + 255) / 256, 256, 0, stream>>>(
        x_dev, p1wr_wl, p1rv_wl, p1wb_wr, p1rb_wr, h_wr, h_rv, root_d, N_DEV);
    pretransform3<<<(N_TASK + 255) / 256, 256, 0, stream>>>(
        x_task, p1wb_wl, p1rb_wl, p1wr_wr, p1rv_wr, h_wb, h_rb, root_t, N_TASK);

    // ---- 3. L1 fused gathers ----
    gather_l1<<<(N_TASK * 16) / 256, 256, 0, stream>>>(
        h_wr, h_rv, rp, eidx, BASE_WR, BASE_RV, root_t, p1wr_bl, p1rv_bl, t1, N_TASK);
    gather_l1<<<(N_DEV * 16) / 256, 256, 0, stream>>>(
        h_wb, h_rb, rp, eidx, BASE_WB, BASE_RB, root_d, p1wb_bl, p1rb_bl, d1, N_DEV);

    // ---- 4. L2 fused gather + matmul -> d_out ----
    gather_l2<<<(N_TASK + 15) / 16, 256, 0, stream>>>(
        d1, d1, rp, eidx, BASE_WR, BASE_RV, t1,
        p2wr_wl, p2rv_wl, p2wr_wr, p2rv_wr, p2wr_bl, p2rv_bl,
        out + (size_t)N_DEV * 32, N_TASK);
    gather_l2<<<(N_DEV + 15) / 16, 256, 0, stream>>>(
        t1, t1, rp, eidx, BASE_WB, BASE_RB, d1,
        p2wb_wl, p2rb_wl, p2wb_wr, p2rb_wr, p2wb_bl, p2rb_bl,
        out, N_DEV);
}

// Round 4
// 1199.193 us; speedup vs baseline: 1.0068x; 1.0068x over previous
//
#include <hip/hip_runtime.h>

// ---------------------------------------------------------------------------
// Hetero 2-layer GraphSAGE — CSR-gather, round 3 (resubmit: R3 bench never ran,
// GPU acquisition timeout).
//
// Round-2 lesson (rocprof): fill4 was HBM-writeback-bound (281 MB WRITE_SIZE
// vs 21 MB footprint, 17x amplification from partially-dirty eidx lines being
// evicted by 32 MB of streaming src/dst reads). Fixes this round:
//   * per-relation fill dispatches (resident dirty set 6 MB << 32 MB L2)
//   * nontemporal loads for all streaming edge data (no L2 pollution)
//   * scan writes cursor directly (no d2d memcpy)
//   * shfl-batched gather (coalesced eidx loads, 16 independent h-rows in
//     flight per node instead of a serial dependent chain)
//   * pretransform does 2 nodes/thread (LDS weight reads amortized, FMA-bound)
// ---------------------------------------------------------------------------

#define N_DEV   100000
#define N_TASK  500000
#define NEDGE   1000000
#define NCNT    1200000          // 500K (wr) + 500K (rv) + 100K (wb) + 100K (rb)
#define BASE_WR 0
#define BASE_RV 500000
#define BASE_WB 1000000
#define BASE_RB 1100000

#define SCAN_PER   16
#define SCAN_CHUNK 4096          // 256 threads * 16
#define SCAN_NBLK  293           // ceil(1.2M / 4096)

struct EdgePtrs {
    const int* dst0; const int* dst1; const int* dst2; const int* dst3;
};

// ---- CSR step 1: histogram over 4 relations (blockIdx.y = relation) ----
__global__ __launch_bounds__(256) void hist4(EdgePtrs ep, int* __restrict__ cnt)
{
    const int e = blockIdx.x * 256 + threadIdx.x;
    if (e >= NEDGE) return;
    const int y = blockIdx.y;
    const int* dst = y == 0 ? ep.dst0 : y == 1 ? ep.dst1 : y == 2 ? ep.dst2 : ep.dst3;
    const int base = y == 0 ? BASE_WR : y == 1 ? BASE_RV : y == 2 ? BASE_WB : BASE_RB;
    const int d = __builtin_nontemporal_load(dst + e);
    atomicAdd(&cnt[base + d], 1);
}

// ---- CSR step 2a: per-block sums of counters ----
__global__ __launch_bounds__(256) void scan_block_sums(
    const int* __restrict__ c, int* __restrict__ bsum)
{
    __shared__ int sm[256];
    const int t = threadIdx.x;
    const int base = blockIdx.x * SCAN_CHUNK + t * SCAN_PER;
    int s = 0;
#pragma unroll
    for (int k = 0; k < SCAN_PER; k += 4) {
        const int idx = base + k;
        if (idx + 3 < NCNT) {
            const int4 v = *reinterpret_cast<const int4*>(&c[idx]);
            s += v.x + v.y + v.z + v.w;
        } else {
            for (int q = 0; q < 4; ++q) if (idx + q < NCNT) s += c[idx + q];
        }
    }
    sm[t] = s;
    __syncthreads();
    for (int off = 128; off > 0; off >>= 1) {
        if (t < off) sm[t] += sm[t + off];
        __syncthreads();
    }
    if (t == 0) bsum[blockIdx.x] = sm[0];
}

// ---- CSR step 2b: exclusive scan of block sums (single block) ----
__global__ __launch_bounds__(512) void scan_bsum(int* __restrict__ bsum)
{
    __shared__ int sm[512];
    const int t = threadIdx.x;
    const int own = (t < SCAN_NBLK) ? bsum[t] : 0;
    sm[t] = own;
    __syncthreads();
    for (int off = 1; off < 512; off <<= 1) {
        int v = sm[t];
        if (t >= off) v += sm[t - off];
        __syncthreads();
        sm[t] = v;
        __syncthreads();
    }
    if (t < SCAN_NBLK) bsum[t] = sm[t] - own;   // exclusive
}

// ---- CSR step 2c: final exclusive scan -> row_ptr AND cursor ----
__global__ __launch_bounds__(256) void scan_final(
    const int* __restrict__ c, const int* __restrict__ bsum,
    int* __restrict__ rp, int* __restrict__ cursor)
{
    __shared__ int sm[256];
    const int t = threadIdx.x;
    const int base = blockIdx.x * SCAN_CHUNK + t * SCAN_PER;
    int vals[SCAN_PER];
    int s = 0;
#pragma unroll
    for (int k = 0; k < SCAN_PER; k += 4) {
        const int idx = base + k;
        int4 v = make_int4(0, 0, 0, 0);
        if (idx + 3 < NCNT) {
            v = *reinterpret_cast<const int4*>(&c[idx]);
        } else {
            if (idx + 0 < NCNT) v.x = c[idx + 0];
            if (idx + 1 < NCNT) v.y = c[idx + 1];
            if (idx + 2 < NCNT) v.z = c[idx + 2];
            if (idx + 3 < NCNT) v.w = c[idx + 3];
        }
        vals[k + 0] = v.x; vals[k + 1] = v.y; vals[k + 2] = v.z; vals[k + 3] = v.w;
        s += v.x + v.y + v.z + v.w;
    }
    const int own = s;
    sm[t] = own;
    __syncthreads();
    for (int off = 1; off < 256; off <<= 1) {
        int v = sm[t];
        if (t >= off) v += sm[t - off];
        __syncthreads();
        sm[t] = v;
        __syncthreads();
    }
    int run = sm[t] - own + bsum[blockIdx.x];
#pragma unroll
    for (int k = 0; k < SCAN_PER; ++k) {
        if (base + k < NCNT) { rp[base + k] = run; cursor[base + k] = run; }
        run += vals[k];
    }
    if (blockIdx.x == 0 && t == 0) rp[NCNT] = 4 * NEDGE;
}

// ---- CSR step 3: per-relation fill (nt loads keep L2 for eidx lines) ----
__global__ __launch_bounds__(256) void fill_rel(
    const int* __restrict__ src, const int* __restrict__ dst, int base,
    int* __restrict__ cursor, int* __restrict__ eidx)
{
    const int e = blockIdx.x * 256 + threadIdx.x;
    if (e >= NEDGE) return;
    const int d = __builtin_nontemporal_load(dst + e);
    const int s = __builtin_nontemporal_load(src + e);
    const int pos = atomicAdd(&cursor[base + d], 1);
    eidx[pos] = s;
}

// ---- pretransform: 2 nodes/thread. outA=x@WA, outB=x@WB, outC=x@(WC1+WC2) ----
__global__ __launch_bounds__(256) void pretransform2(
    const float* __restrict__ x,
    const float* __restrict__ WA, const float* __restrict__ WB,
    const float* __restrict__ WC1, const float* __restrict__ WC2,
    float* __restrict__ outA, float* __restrict__ outB, float* __restrict__ outC,
    int n)
{
    __shared__ float wA[64 * 16], wB[64 * 16], wC[64 * 16];
    const int t = threadIdx.x;
    for (int i = t; i < 64 * 16; i += 256) {
        wA[i] = WA[i];
        wB[i] = WB[i];
        wC[i] = WC1[i] + WC2[i];
    }
    __syncthreads();

    const int n0 = blockIdx.x * 512 + t;
    const int n1 = n0 + 256;
    if (n0 >= n) return;
    const bool v1 = (n1 < n);

    float a0[16], b0[16], c0[16], a1[16], b1[16], c1[16];
#pragma unroll
    for (int i = 0; i < 16; ++i) {
        a0[i] = b0[i] = c0[i] = 0.f;
        a1[i] = b1[i] = c1[i] = 0.f;
    }

    const float4* xr0 = reinterpret_cast<const float4*>(&x[(size_t)n0 * 64]);
    const float4* xr1 = v1 ? reinterpret_cast<const float4*>(&x[(size_t)n1 * 64]) : xr0;

    for (int k4 = 0; k4 < 16; ++k4) {
        const float4 xv0 = xr0[k4];
        const float4 xv1 = xr1[k4];
#pragma unroll
        for (int q = 0; q < 4; ++q) {
            const int k = k4 * 4 + q;
            const float x0 = (q == 0) ? xv0.x : (q == 1) ? xv0.y : (q == 2) ? xv0.z : xv0.w;
            const float x1 = (q == 0) ? xv1.x : (q == 1) ? xv1.y : (q == 2) ? xv1.z : xv1.w;
#pragma unroll
            for (int cix = 0; cix < 16; ++cix) {
                const float wa = wA[k * 16 + cix];
                const float wb = wB[k * 16 + cix];
                const float wc = wC[k * 16 + cix];
                a0[cix] = fmaf(x0, wa, a0[cix]);
                b0[cix] = fmaf(x0, wb, b0[cix]);
                c0[cix] = fmaf(x0, wc, c0[cix]);
                a1[cix] = fmaf(x1, wa, a1[cix]);
                b1[cix] = fmaf(x1, wb, b1[cix]);
                c1[cix] = fmaf(x1, wc, c1[cix]);
            }
        }
    }
    float4* oA0 = reinterpret_cast<float4*>(&outA[(size_t)n0 * 16]);
    float4* oB0 = reinterpret_cast<float4*>(&outB[(size_t)n0 * 16]);
    float4* oC0 = reinterpret_cast<float4*>(&outC[(size_t)n0 * 16]);
#pragma unroll
    for (int i = 0; i < 4; ++i) {
        oA0[i] = make_float4(a0[i*4], a0[i*4+1], a0[i*4+2], a0[i*4+3]);
        oB0[i] = make_float4(b0[i*4], b0[i*4+1], b0[i*4+2], b0[i*4+3]);
        oC0[i] = make_float4(c0[i*4], c0[i*4+1], c0[i*4+2], c0[i*4+3]);
    }
    if (v1) {
        float4* oA1 = reinterpret_cast<float4*>(&outA[(size_t)n1 * 16]);
        float4* oB1 = reinterpret_cast<float4*>(&outB[(size_t)n1 * 16]);
        float4* oC1 = reinterpret_cast<float4*>(&outC[(size_t)n1 * 16]);
#pragma unroll
        for (int i = 0; i < 4; ++i) {
            oA1[i] = make_float4(a1[i*4], a1[i*4+1], a1[i*4+2], a1[i*4+3]);
            oB1[i] = make_float4(b1[i*4], b1[i*4+1], b1[i*4+2], b1[i*4+3]);
            oC1[i] = make_float4(c1[i*4], c1[i*4+1], c1[i*4+2], c1[i*4+3]);
        }
    }
}

// ---- shfl-batched mean gather for one relation (16 lanes per node) ----
__device__ __forceinline__ float gather_mean16(
    const float* __restrict__ h, const int* __restrict__ eidx,
    int e0, int e1, int j)
{
    float acc = 0.f;
    for (int base_e = e0; base_e < e1; base_e += 16) {
        const int m = min(16, e1 - base_e);
        const int se = (j < m) ? __builtin_nontemporal_load(eidx + base_e + j) : 0;
        for (int b = 0; b < m; ++b) {
            const int s = __shfl(se, b, 16);
            acc += h[(size_t)s * 16 + j];
        }
    }
    return acc * (1.f / fmaxf((float)(e1 - e0), 1.f));
}

// ---- L1 fused gather: out = relu(mean_A + mean_B + root + bA + bB) ----
__global__ __launch_bounds__(256) void gather_l1(
    const float* __restrict__ hA, const float* __restrict__ hB,
    const int* __restrict__ rp, const int* __restrict__ eidx,
    int baseA, int baseB,
    const float* __restrict__ root,
    const float* __restrict__ bA, const float* __restrict__ bB,
    float* __restrict__ out, int n)
{
    const int t = blockIdx.x * 256 + threadIdx.x;
    const int i = t >> 4;
    const int j = t & 15;
    if (i >= n) return;

    const int a0 = rp[baseA + i], a1 = rp[baseA + i + 1];
    const int b0 = rp[baseB + i], b1 = rp[baseB + i + 1];

    const float mA = gather_mean16(hA, eidx, a0, a1, j);
    const float mB = gather_mean16(hB, eidx, b0, b1, j);

    const float v = mA + mB + root[(size_t)i * 16 + j] + bA[j] + bB[j];
    out[(size_t)i * 16 + j] = fmaxf(v, 0.f);
}

// ---- L2 fused gather + 16->32 matmul. 16 nodes/block, 16 lanes/node ----
__global__ __launch_bounds__(256) void gather_l2(
    const float* __restrict__ hA, const float* __restrict__ hB,
    const int* __restrict__ rp, const int* __restrict__ eidx,
    int baseA, int baseB,
    const float* __restrict__ xroot,
    const float* __restrict__ WA, const float* __restrict__ WB,
    const float* __restrict__ WR1, const float* __restrict__ WR2,
    const float* __restrict__ bA, const float* __restrict__ bB,
    float* __restrict__ out, int n)
{
    __shared__ float wA[512], wB[512], wR[512], bs[32];
    __shared__ float smA[16][17], smB[16][17], smR[16][17];

    const int t = threadIdx.x;
    for (int i = t; i < 512; i += 256) {
        wA[i] = WA[i];
        wB[i] = WB[i];
        wR[i] = WR1[i] + WR2[i];
    }
    if (t < 32) bs[t] = bA[t] + bB[t];

    const int g = t >> 4;
    const int j = t & 15;
    const int i = blockIdx.x * 16 + g;

    float mA = 0.f, mB = 0.f, r = 0.f;
    if (i < n) {
        const int a0 = rp[baseA + i], a1 = rp[baseA + i + 1];
        const int b0 = rp[baseB + i], b1 = rp[baseB + i + 1];
        mA = gather_mean16(hA, eidx, a0, a1, j);
        mB = gather_mean16(hB, eidx, b0, b1, j);
        r = xroot[(size_t)i * 16 + j];
    }
    smA[g][j] = mA;
    smB[g][j] = mB;
    smR[g][j] = r;
    __syncthreads();

    if (i >= n) return;
    float acc0 = bs[j], acc1 = bs[j + 16];
#pragma unroll
    for (int k = 0; k < 16; ++k) {
        const float a = smA[g][k], b = smB[g][k], rr = smR[g][k];
        acc0 = fmaf(a,  wA[k * 32 + j],      acc0);
        acc1 = fmaf(a,  wA[k * 32 + j + 16], acc1);
        acc0 = fmaf(b,  wB[k * 32 + j],      acc0);
        acc1 = fmaf(b,  wB[k * 32 + j + 16], acc1);
        acc0 = fmaf(rr, wR[k * 32 + j],      acc0);
        acc1 = fmaf(rr, wR[k * 32 + j + 16], acc1);
    }
    out[(size_t)i * 32 + j]      = acc0;
    out[(size_t)i * 32 + j + 16] = acc1;
}

extern "C" void kernel_launch(void* const* d_in, const int* in_sizes, int n_in,
                              void* d_out, int out_size, void* d_ws, size_t ws_size,
                              hipStream_t stream)
{
    const float* x_dev  = (const float*)d_in[0];
    const float* x_task = (const float*)d_in[1];
    const int* wr_src = (const int*)d_in[2];
    const int* wr_dst = (const int*)d_in[3];
    const int* rv_src = (const int*)d_in[4];
    const int* rv_dst = (const int*)d_in[5];
    const int* wb_src = (const int*)d_in[6];
    const int* wb_dst = (const int*)d_in[7];
    const int* rb_src = (const int*)d_in[8];
    const int* rb_dst = (const int*)d_in[9];
    const float* p1wr_wl = (const float*)d_in[10];
    const float* p1wr_bl = (const float*)d_in[11];
    const float* p1wr_wr = (const float*)d_in[12];
    const float* p1rv_wl = (const float*)d_in[13];
    const float* p1rv_bl = (const float*)d_in[14];
    const float* p1rv_wr = (const float*)d_in[15];
    const float* p1wb_wl = (const float*)d_in[16];
    const float* p1wb_bl = (const float*)d_in[17];
    const float* p1wb_wr = (const float*)d_in[18];
    const float* p1rb_wl = (const float*)d_in[19];
    const float* p1rb_bl = (const float*)d_in[20];
    const float* p1rb_wr = (const float*)d_in[21];
    const float* p2wr_wl = (const float*)d_in[22];
    const float* p2wr_bl = (const float*)d_in[23];
    const float* p2wr_wr = (const float*)d_in[24];
    const float* p2rv_wl = (const float*)d_in[25];
    const float* p2rv_bl = (const float*)d_in[26];
    const float* p2rv_wr = (const float*)d_in[27];
    const float* p2wb_wl = (const float*)d_in[28];
    const float* p2wb_bl = (const float*)d_in[29];
    const float* p2wb_wr = (const float*)d_in[30];
    const float* p2rb_wl = (const float*)d_in[31];
    const float* p2rb_bl = (const float*)d_in[32];
    const float* p2rb_wr = (const float*)d_in[33];

    // ---- workspace carve-up ----
    int* wsI = (int*)d_ws;
    int* cnt    = wsI + 0;          // 1.2M
    int* rp     = wsI + 1200000;    // 1.2M + 1
    int* cursor = wsI + 2400004;    // 1.2M
    int* eidx   = wsI + 3600004;    // 4M
    int* bsum   = wsI + 7600004;    // 512
    float* wsF = (float*)d_ws + 7700000;   // 16B-aligned float region
    float* h_wr   = wsF + 0;         // dev  x16
    float* h_rv   = wsF + 1600000;   // dev  x16
    float* h_wb   = wsF + 3200000;   // task x16
    float* h_rb   = wsF + 11200000;  // task x16
    float* root_d = wsF + 19200000;  // dev  x16
    float* root_t = wsF + 20800000;  // task x16
    float* t1     = wsF + 28800000;  // task x16
    float* d1     = wsF + 36800000;  // dev  x16

    float* out = (float*)d_out;      // [d2: 100K x32 | t2: 500K x32]

    EdgePtrs ep;
    ep.dst0 = wr_dst; ep.dst1 = rv_dst; ep.dst2 = wb_dst; ep.dst3 = rb_dst;

    const int eblk = (NEDGE + 255) / 256;

    // ---- 1. CSR build ----
    hipMemsetAsync(cnt, 0, (size_t)NCNT * sizeof(int), stream);
    hist4<<<dim3(eblk, 4), 256, 0, stream>>>(ep, cnt);
    scan_block_sums<<<SCAN_NBLK, 256, 0, stream>>>(cnt, bsum);
    scan_bsum<<<1, 512, 0, stream>>>(bsum);
    scan_final<<<SCAN_NBLK, 256, 0, stream>>>(cnt, bsum, rp, cursor);
    fill_rel<<<eblk, 256, 0, stream>>>(wr_src, wr_dst, BASE_WR, cursor, eidx);
    fill_rel<<<eblk, 256, 0, stream>>>(rv_src, rv_dst, BASE_RV, cursor, eidx);
    fill_rel<<<eblk, 256, 0, stream>>>(wb_src, wb_dst, BASE_WB, cursor, eidx);
    fill_rel<<<eblk, 256, 0, stream>>>(rb_src, rb_dst, BASE_RB, cursor, eidx);

    // ---- 2. pretransforms (h_rel + summed-root) ----
    pretransform2<<<(N_DEV + 511) / 512, 256, 0, stream>>>(
        x_dev, p1wr_wl, p1rv_wl, p1wb_wr, p1rb_wr, h_wr, h_rv, root_d, N_DEV);
    pretransform2<<<(N_TASK + 511) / 512, 256, 0, stream>>>(
        x_task, p1wb_wl, p1rb_wl, p1wr_wr, p1rv_wr, h_wb, h_rb, root_t, N_TASK);

    // ---- 3. L1 fused gathers ----
    gather_l1<<<(N_TASK * 16) / 256, 256, 0, stream>>>(
        h_wr, h_rv, rp, eidx, BASE_WR, BASE_RV, root_t, p1wr_bl, p1rv_bl, t1, N_TASK);
    gather_l1<<<(N_DEV * 16) / 256, 256, 0, stream>>>(
        h_wb, h_rb, rp, eidx, BASE_WB, BASE_RB, root_d, p1wb_bl, p1rb_bl, d1, N_DEV);

    // ---- 4. L2 fused gather + matmul -> d_out ----
    gather_l2<<<(N_TASK + 15) / 16, 256, 0, stream>>>(
        d1, d1, rp, eidx, BASE_WR, BASE_RV, t1,
        p2wr_wl, p2rv_wl, p2wr_wr, p2rv_wr, p2wr_bl, p2rv_bl,
        out + (size_t)N_DEV * 32, N_TASK);
    gather_l2<<<(N_DEV + 15) / 16, 256, 0, stream>>>(
        t1, t1, rp, eidx, BASE_WB, BASE_RB, d1,
        p2wb_wl, p2rb_wl, p2wb_wr, p2rb_wr, p2wb_bl, p2rb_bl,
        out, N_DEV);
}

// Round 6
// 1103.292 us; speedup vs baseline: 1.0943x; 1.0869x over previous
//
#include <hip/hip_runtime.h>

// ---------------------------------------------------------------------------
// Hetero 2-layer GraphSAGE — CSR-gather, round 5 (resubmit: R5 bench never ran,
// GPU acquisition timeout).
//
// Round-4 lesson (rocprof): pretransform2's per-thread row loads (256 B lane
// stride) caused 3x read amplification (FETCH 374 MB vs 128 MB footprint,
// 3 TB/s at 13% VALUBusy). Fix: coalesced float4 LDS staging (two 32-col
// halves, 45 KB LDS) + uniform-broadcast ds_read_b128 weight reads
// (12 reads : 48 FMAs per k-step). Gathers: 4-deep pipelined chunk loop
// (independent loads in flight) + shfl-dedup of row-pointer loads.
// ~1013 us is hidden below top-5 (fills/gathers/hist) — this round drops
// pretransform out of top-5 to expose them.
// ---------------------------------------------------------------------------

#define N_DEV   100000
#define N_TASK  500000
#define NEDGE   1000000
#define NCNT    1200000          // 500K (wr) + 500K (rv) + 100K (wb) + 100K (rb)
#define BASE_WR 0
#define BASE_RV 500000
#define BASE_WB 1000000
#define BASE_RB 1100000

#define SCAN_PER   16
#define SCAN_CHUNK 4096          // 256 threads * 16
#define SCAN_NBLK  293           // ceil(1.2M / 4096)

struct EdgePtrs {
    const int* dst0; const int* dst1; const int* dst2; const int* dst3;
};

// ---- CSR step 1: histogram over 4 relations (blockIdx.y = relation) ----
__global__ __launch_bounds__(256) void hist4(EdgePtrs ep, int* __restrict__ cnt)
{
    const int e = blockIdx.x * 256 + threadIdx.x;
    if (e >= NEDGE) return;
    const int y = blockIdx.y;
    const int* dst = y == 0 ? ep.dst0 : y == 1 ? ep.dst1 : y == 2 ? ep.dst2 : ep.dst3;
    const int base = y == 0 ? BASE_WR : y == 1 ? BASE_RV : y == 2 ? BASE_WB : BASE_RB;
    const int d = __builtin_nontemporal_load(dst + e);
    atomicAdd(&cnt[base + d], 1);
}

// ---- CSR step 2a: per-block sums of counters ----
__global__ __launch_bounds__(256) void scan_block_sums(
    const int* __restrict__ c, int* __restrict__ bsum)
{
    __shared__ int sm[256];
    const int t = threadIdx.x;
    const int base = blockIdx.x * SCAN_CHUNK + t * SCAN_PER;
    int s = 0;
#pragma unroll
    for (int k = 0; k < SCAN_PER; k += 4) {
        const int idx = base + k;
        if (idx + 3 < NCNT) {
            const int4 v = *reinterpret_cast<const int4*>(&c[idx]);
            s += v.x + v.y + v.z + v.w;
        } else {
            for (int q = 0; q < 4; ++q) if (idx + q < NCNT) s += c[idx + q];
        }
    }
    sm[t] = s;
    __syncthreads();
    for (int off = 128; off > 0; off >>= 1) {
        if (t < off) sm[t] += sm[t + off];
        __syncthreads();
    }
    if (t == 0) bsum[blockIdx.x] = sm[0];
}

// ---- CSR step 2b: exclusive scan of block sums (single block) ----
__global__ __launch_bounds__(512) void scan_bsum(int* __restrict__ bsum)
{
    __shared__ int sm[512];
    const int t = threadIdx.x;
    const int own = (t < SCAN_NBLK) ? bsum[t] : 0;
    sm[t] = own;
    __syncthreads();
    for (int off = 1; off < 512; off <<= 1) {
        int v = sm[t];
        if (t >= off) v += sm[t - off];
        __syncthreads();
        sm[t] = v;
        __syncthreads();
    }
    if (t < SCAN_NBLK) bsum[t] = sm[t] - own;   // exclusive
}

// ---- CSR step 2c: final exclusive scan -> row_ptr AND cursor ----
__global__ __launch_bounds__(256) void scan_final(
    const int* __restrict__ c, const int* __restrict__ bsum,
    int* __restrict__ rp, int* __restrict__ cursor)
{
    __shared__ int sm[256];
    const int t = threadIdx.x;
    const int base = blockIdx.x * SCAN_CHUNK + t * SCAN_PER;
    int vals[SCAN_PER];
    int s = 0;
#pragma unroll
    for (int k = 0; k < SCAN_PER; k += 4) {
        const int idx = base + k;
        int4 v = make_int4(0, 0, 0, 0);
        if (idx + 3 < NCNT) {
            v = *reinterpret_cast<const int4*>(&c[idx]);
        } else {
            if (idx + 0 < NCNT) v.x = c[idx + 0];
            if (idx + 1 < NCNT) v.y = c[idx + 1];
            if (idx + 2 < NCNT) v.z = c[idx + 2];
            if (idx + 3 < NCNT) v.w = c[idx + 3];
        }
        vals[k + 0] = v.x; vals[k + 1] = v.y; vals[k + 2] = v.z; vals[k + 3] = v.w;
        s += v.x + v.y + v.z + v.w;
    }
    const int own = s;
    sm[t] = own;
    __syncthreads();
    for (int off = 1; off < 256; off <<= 1) {
        int v = sm[t];
        if (t >= off) v += sm[t - off];
        __syncthreads();
        sm[t] = v;
        __syncthreads();
    }
    int run = sm[t] - own + bsum[blockIdx.x];
#pragma unroll
    for (int k = 0; k < SCAN_PER; ++k) {
        if (base + k < NCNT) { rp[base + k] = run; cursor[base + k] = run; }
        run += vals[k];
    }
    if (blockIdx.x == 0 && t == 0) rp[NCNT] = 4 * NEDGE;
}

// ---- CSR step 3: per-relation fill ----
__global__ __launch_bounds__(256) void fill_rel(
    const int* __restrict__ src, const int* __restrict__ dst, int base,
    int* __restrict__ cursor, int* __restrict__ eidx)
{
    const int e = blockIdx.x * 256 + threadIdx.x;
    if (e >= NEDGE) return;
    const int d = __builtin_nontemporal_load(dst + e);
    const int s = __builtin_nontemporal_load(src + e);
    const int pos = atomicAdd(&cursor[base + d], 1);
    eidx[pos] = s;
}

// ---- pretransform v3: coalesced LDS staging + broadcast b128 weight reads.
// outA = x@WA, outB = x@WB, outC = x@(WC1+WC2).  1 node/thread, 256/block.
__global__ __launch_bounds__(256) void pretransform_v3(
    const float* __restrict__ x,
    const float* __restrict__ WA, const float* __restrict__ WB,
    const float* __restrict__ WC1, const float* __restrict__ WC2,
    float* __restrict__ outA, float* __restrict__ outB, float* __restrict__ outC,
    int n)
{
    __shared__ float xs[256][33];                 // 32 cols + 1 pad (bank spread)
    __shared__ float wAs[1024], wBs[1024], wCs[1024];

    const int t = threadIdx.x;
    for (int i = t; i < 1024; i += 256) {
        wAs[i] = WA[i];
        wBs[i] = WB[i];
        wCs[i] = WC1[i] + WC2[i];
    }

    const int node0 = blockIdx.x * 256;
    const int nrow  = min(256, n - node0);

    float a[16], b[16], c[16];
#pragma unroll
    for (int i = 0; i < 16; ++i) { a[i] = 0.f; b[i] = 0.f; c[i] = 0.f; }

    for (int half = 0; half < 2; ++half) {
        __syncthreads();   // xs reuse barrier (also covers w staging, half 0)
        // stage cols [half*32, half*32+32) for nrow nodes, coalesced float4
#pragma unroll
        for (int it = 0; it < 8; ++it) {
            const int f = it * 1024 + t * 4;      // 0..8191
            const int r = f >> 5, cc = f & 31;
            if (r < nrow) {
                const float4 v = *reinterpret_cast<const float4*>(
                    &x[(size_t)(node0 + r) * 64 + half * 32 + cc]);
                xs[r][cc + 0] = v.x;
                xs[r][cc + 1] = v.y;
                xs[r][cc + 2] = v.z;
                xs[r][cc + 3] = v.w;
            }
        }
        __syncthreads();

        if (t < nrow) {
            for (int kk = 0; kk < 32; ++kk) {
                const int k = half * 32 + kk;
                const float xv = xs[t][kk];
                const float4* wa4 = reinterpret_cast<const float4*>(&wAs[k * 16]);
                const float4* wb4 = reinterpret_cast<const float4*>(&wBs[k * 16]);
                const float4* wc4 = reinterpret_cast<const float4*>(&wCs[k * 16]);
#pragma unroll
                for (int q = 0; q < 4; ++q) {
                    const float4 wa = wa4[q], wb = wb4[q], wc = wc4[q];
                    a[q*4+0] = fmaf(xv, wa.x, a[q*4+0]);
                    a[q*4+1] = fmaf(xv, wa.y, a[q*4+1]);
                    a[q*4+2] = fmaf(xv, wa.z, a[q*4+2]);
                    a[q*4+3] = fmaf(xv, wa.w, a[q*4+3]);
                    b[q*4+0] = fmaf(xv, wb.x, b[q*4+0]);
                    b[q*4+1] = fmaf(xv, wb.y, b[q*4+1]);
                    b[q*4+2] = fmaf(xv, wb.z, b[q*4+2]);
                    b[q*4+3] = fmaf(xv, wb.w, b[q*4+3]);
                    c[q*4+0] = fmaf(xv, wc.x, c[q*4+0]);
                    c[q*4+1] = fmaf(xv, wc.y, c[q*4+1]);
                    c[q*4+2] = fmaf(xv, wc.z, c[q*4+2]);
                    c[q*4+3] = fmaf(xv, wc.w, c[q*4+3]);
                }
            }
        }
    }

    if (t < nrow) {
        const int node = node0 + t;
        float4* oA = reinterpret_cast<float4*>(&outA[(size_t)node * 16]);
        float4* oB = reinterpret_cast<float4*>(&outB[(size_t)node * 16]);
        float4* oC = reinterpret_cast<float4*>(&outC[(size_t)node * 16]);
#pragma unroll
        for (int i = 0; i < 4; ++i) {
            oA[i] = make_float4(a[i*4], a[i*4+1], a[i*4+2], a[i*4+3]);
            oB[i] = make_float4(b[i*4], b[i*4+1], b[i*4+2], b[i*4+3]);
            oC[i] = make_float4(c[i*4], c[i*4+1], c[i*4+2], c[i*4+3]);
        }
    }
}

// ---- 4-deep pipelined mean gather (16 lanes per node) ----
__device__ __forceinline__ float gather_mean16(
    const float* __restrict__ h, const int* __restrict__ eidx,
    int e0, int e1, int j)
{
    float acc = 0.f;
    int e = e0;
    for (; e + 4 <= e1; e += 4) {
        const int s0 = eidx[e + 0];
        const int s1 = eidx[e + 1];
        const int s2 = eidx[e + 2];
        const int s3 = eidx[e + 3];
        const float v0 = h[(size_t)s0 * 16 + j];
        const float v1 = h[(size_t)s1 * 16 + j];
        const float v2 = h[(size_t)s2 * 16 + j];
        const float v3 = h[(size_t)s3 * 16 + j];
        acc += (v0 + v1) + (v2 + v3);
    }
    if (e + 2 <= e1) {
        const int s0 = eidx[e + 0];
        const int s1 = eidx[e + 1];
        acc += h[(size_t)s0 * 16 + j] + h[(size_t)s1 * 16 + j];
        e += 2;
    }
    if (e < e1) acc += h[(size_t)eidx[e] * 16 + j];
    return acc * (1.f / fmaxf((float)(e1 - e0), 1.f));
}

// ---- L1 fused gather: out = relu(mean_A + mean_B + root + bA + bB) ----
__global__ __launch_bounds__(256) void gather_l1(
    const float* __restrict__ hA, const float* __restrict__ hB,
    const int* __restrict__ rp, const int* __restrict__ eidx,
    int baseA, int baseB,
    const float* __restrict__ root,
    const float* __restrict__ bA, const float* __restrict__ bB,
    float* __restrict__ out, int n)
{
    const int t = blockIdx.x * 256 + threadIdx.x;
    const int i = t >> 4;
    const int j = t & 15;
    if (i >= n) return;

    // shfl-dedup of the 4 row-pointer loads (1 load per lane j<4)
    int v = 0;
    if (j < 4) v = rp[((j & 2) ? baseB : baseA) + i + (j & 1)];
    const int a0 = __shfl(v, 0, 16);
    const int a1 = __shfl(v, 1, 16);
    const int b0 = __shfl(v, 2, 16);
    const int b1 = __shfl(v, 3, 16);

    const float mA = gather_mean16(hA, eidx, a0, a1, j);
    const float mB = gather_mean16(hB, eidx, b0, b1, j);

    const float r = mA + mB + root[(size_t)i * 16 + j] + bA[j] + bB[j];
    out[(size_t)i * 16 + j] = fmaxf(r, 0.f);
}

// ---- L2 fused gather + 16->32 matmul. 16 nodes/block, 16 lanes/node ----
__global__ __launch_bounds__(256) void gather_l2(
    const float* __restrict__ hA, const float* __restrict__ hB,
    const int* __restrict__ rp, const int* __restrict__ eidx,
    int baseA, int baseB,
    const float* __restrict__ xroot,
    const float* __restrict__ WA, const float* __restrict__ WB,
    const float* __restrict__ WR1, const float* __restrict__ WR2,
    const float* __restrict__ bA, const float* __restrict__ bB,
    float* __restrict__ out, int n)
{
    __shared__ float wA[512], wB[512], wR[512], bs[32];
    __shared__ float smA[16][17], smB[16][17], smR[16][17];

    const int t = threadIdx.x;
    for (int i = t; i < 512; i += 256) {
        wA[i] = WA[i];
        wB[i] = WB[i];
        wR[i] = WR1[i] + WR2[i];
    }
    if (t < 32) bs[t] = bA[t] + bB[t];

    const int g = t >> 4;
    const int j = t & 15;
    const int i = blockIdx.x * 16 + g;

    float mA = 0.f, mB = 0.f, r = 0.f;
    if (i < n) {
        int v = 0;
        if (j < 4) v = rp[((j & 2) ? baseB : baseA) + i + (j & 1)];
        const int a0 = __shfl(v, 0, 16);
        const int a1 = __shfl(v, 1, 16);
        const int b0 = __shfl(v, 2, 16);
        const int b1 = __shfl(v, 3, 16);
        mA = gather_mean16(hA, eidx, a0, a1, j);
        mB = gather_mean16(hB, eidx, b0, b1, j);
        r = xroot[(size_t)i * 16 + j];
    }
    smA[g][j] = mA;
    smB[g][j] = mB;
    smR[g][j] = r;
    __syncthreads();

    if (i >= n) return;
    float acc0 = bs[j], acc1 = bs[j + 16];
#pragma unroll
    for (int k = 0; k < 16; ++k) {
        const float a = smA[g][k], b = smB[g][k], rr = smR[g][k];
        acc0 = fmaf(a,  wA[k * 32 + j],      acc0);
        acc1 = fmaf(a,  wA[k * 32 + j + 16], acc1);
        acc0 = fmaf(b,  wB[k * 32 + j],      acc0);
        acc1 = fmaf(b,  wB[k * 32 + j + 16], acc1);
        acc0 = fmaf(rr, wR[k * 32 + j],      acc0);
        acc1 = fmaf(rr, wR[k * 32 + j + 16], acc1);
    }
    out[(size_t)i * 32 + j]      = acc0;
    out[(size_t)i * 32 + j + 16] = acc1;
}

extern "C" void kernel_launch(void* const* d_in, const int* in_sizes, int n_in,
                              void* d_out, int out_size, void* d_ws, size_t ws_size,
                              hipStream_t stream)
{
    const float* x_dev  = (const float*)d_in[0];
    const float* x_task = (const float*)d_in[1];
    const int* wr_src = (const int*)d_in[2];
    const int* wr_dst = (const int*)d_in[3];
    const int* rv_src = (const int*)d_in[4];
    const int* rv_dst = (const int*)d_in[5];
    const int* wb_src = (const int*)d_in[6];
    const int* wb_dst = (const int*)d_in[7];
    const int* rb_src = (const int*)d_in[8];
    const int* rb_dst = (const int*)d_in[9];
    const float* p1wr_wl = (const float*)d_in[10];
    const float* p1wr_bl = (const float*)d_in[11];
    const float* p1wr_wr = (const float*)d_in[12];
    const float* p1rv_wl = (const float*)d_in[13];
    const float* p1rv_bl = (const float*)d_in[14];
    const float* p1rv_wr = (const float*)d_in[15];
    const float* p1wb_wl = (const float*)d_in[16];
    const float* p1wb_bl = (const float*)d_in[17];
    const float* p1wb_wr = (const float*)d_in[18];
    const float* p1rb_wl = (const float*)d_in[19];
    const float* p1rb_bl = (const float*)d_in[20];
    const float* p1rb_wr = (const float*)d_in[21];
    const float* p2wr_wl = (const float*)d_in[22];
    const float* p2wr_bl = (const float*)d_in[23];
    const float* p2wr_wr = (const float*)d_in[24];
    const float* p2rv_wl = (const float*)d_in[25];
    const float* p2rv_bl = (const float*)d_in[26];
    const float* p2rv_wr = (const float*)d_in[27];
    const float* p2wb_wl = (const float*)d_in[28];
    const float* p2wb_bl = (const float*)d_in[29];
    const float* p2wb_wr = (const float*)d_in[30];
    const float* p2rb_wl = (const float*)d_in[31];
    const float* p2rb_bl = (const float*)d_in[32];
    const float* p2rb_wr = (const float*)d_in[33];

    // ---- workspace carve-up ----
    int* wsI = (int*)d_ws;
    int* cnt    = wsI + 0;          // 1.2M
    int* rp     = wsI + 1200000;    // 1.2M + 1
    int* cursor = wsI + 2400004;    // 1.2M
    int* eidx   = wsI + 3600004;    // 4M
    int* bsum   = wsI + 7600004;    // 512
    float* wsF = (float*)d_ws + 7700000;   // 16B-aligned float region
    float* h_wr   = wsF + 0;         // dev  x16
    float* h_rv   = wsF + 1600000;   // dev  x16
    float* h_wb   = wsF + 3200000;   // task x16
    float* h_rb   = wsF + 11200000;  // task x16
    float* root_d = wsF + 19200000;  // dev  x16
    float* root_t = wsF + 20800000;  // task x16
    float* t1     = wsF + 28800000;  // task x16
    float* d1     = wsF + 36800000;  // dev  x16

    float* out = (float*)d_out;      // [d2: 100K x32 | t2: 500K x32]

    EdgePtrs ep;
    ep.dst0 = wr_dst; ep.dst1 = rv_dst; ep.dst2 = wb_dst; ep.dst3 = rb_dst;

    const int eblk = (NEDGE + 255) / 256;

    // ---- 1. CSR build ----
    hipMemsetAsync(cnt, 0, (size_t)NCNT * sizeof(int), stream);
    hist4<<<dim3(eblk, 4), 256, 0, stream>>>(ep, cnt);
    scan_block_sums<<<SCAN_NBLK, 256, 0, stream>>>(cnt, bsum);
    scan_bsum<<<1, 512, 0, stream>>>(bsum);
    scan_final<<<SCAN_NBLK, 256, 0, stream>>>(cnt, bsum, rp, cursor);
    fill_rel<<<eblk, 256, 0, stream>>>(wr_src, wr_dst, BASE_WR, cursor, eidx);
    fill_rel<<<eblk, 256, 0, stream>>>(rv_src, rv_dst, BASE_RV, cursor, eidx);
    fill_rel<<<eblk, 256, 0, stream>>>(wb_src, wb_dst, BASE_WB, cursor, eidx);
    fill_rel<<<eblk, 256, 0, stream>>>(rb_src, rb_dst, BASE_RB, cursor, eidx);

    // ---- 2. pretransforms (h_rel + summed-root) ----
    pretransform_v3<<<(N_DEV + 255) / 256, 256, 0, stream>>>(
        x_dev, p1wr_wl, p1rv_wl, p1wb_wr, p1rb_wr, h_wr, h_rv, root_d, N_DEV);
    pretransform_v3<<<(N_TASK + 255) / 256, 256, 0, stream>>>(
        x_task, p1wb_wl, p1rb_wl, p1wr_wr, p1rv_wr, h_wb, h_rb, root_t, N_TASK);

    // ---- 3. L1 fused gathers ----
    gather_l1<<<(N_TASK * 16) / 256, 256, 0, stream>>>(
        h_wr, h_rv, rp, eidx, BASE_WR, BASE_RV, root_t, p1wr_bl, p1rv_bl, t1, N_TASK);
    gather_l1<<<(N_DEV * 16) / 256, 256, 0, stream>>>(
        h_wb, h_rb, rp, eidx, BASE_WB, BASE_RB, root_d, p1wb_bl, p1rb_bl, d1, N_DEV);

    // ---- 4. L2 fused gather + matmul -> d_out ----
    gather_l2<<<(N_TASK + 15) / 16, 256, 0, stream>>>(
        d1, d1, rp, eidx, BASE_WR, BASE_RV, t1,
        p2wr_wl, p2rv_wl, p2wr_wr, p2rv_wr, p2wr_bl, p2rv_bl,
        out + (size_t)N_DEV * 32, N_TASK);
    gather_l2<<<(N_DEV + 15) / 16, 256, 0, stream>>>(
        t1, t1, rp, eidx, BASE_WB, BASE_RB, d1,
        p2wb_wl, p2rb_wl, p2wb_wr, p2rb_wr, p2wb_bl, p2rb_bl,
        out, N_DEV);
}

// Round 7
// 990.640 us; speedup vs baseline: 1.2187x; 1.1137x over previous
//
#include <hip/hip_runtime.h>

// ---------------------------------------------------------------------------
// Hetero 2-layer GraphSAGE — CSR-gather, round 7.
//
// Round-6 lesson (rocprof): random-line global atomics are write-through at
// ~31 B/op at the memory-side coherence point (hist4: 4M ops -> 124.8 MB
// WRITE_SIZE vs 4.8 MB footprint). Op count is the cost driver.
//   * rank trick: hist captures rank[e] = atomicAdd(cnt[d],1); fill becomes
//     atomic-free (pos = rp[d] + rank[e]).  8M -> 4M atomic ops.
//   * hist split per-relation (4 dispatches) for profile granularity: top-5
//     with graph replays only shows the max dispatch; splitting the 154 us
//     hist lets the hidden ~500 us distribution surface.
//   * gathers: 32 lanes/node — both relations' dependent-load chains in
//     parallel lane-halves; shfl_xor(16) merge (L1) / per-half LDS (L2).
// ---------------------------------------------------------------------------

#define N_DEV   100000
#define N_TASK  500000
#define NEDGE   1000000
#define NCNT    1200000          // 500K (wr) + 500K (rv) + 100K (wb) + 100K (rb)
#define BASE_WR 0
#define BASE_RV 500000
#define BASE_WB 1000000
#define BASE_RB 1100000

#define SCAN_PER   16
#define SCAN_CHUNK 4096          // 256 threads * 16
#define SCAN_NBLK  293           // ceil(1.2M / 4096)

// ---- CSR step 1: per-relation histogram + per-edge rank capture ----
__global__ __launch_bounds__(256) void hist_rank_rel(
    const int* __restrict__ dst, int base,
    int* __restrict__ cnt, int* __restrict__ rank)
{
    const int e = blockIdx.x * 256 + threadIdx.x;
    if (e >= NEDGE) return;
    const int d = __builtin_nontemporal_load(dst + e);
    rank[e] = atomicAdd(&cnt[base + d], 1);
}

// ---- CSR step 2a: per-block sums of counters ----
__global__ __launch_bounds__(256) void scan_block_sums(
    const int* __restrict__ c, int* __restrict__ bsum)
{
    __shared__ int sm[256];
    const int t = threadIdx.x;
    const int base = blockIdx.x * SCAN_CHUNK + t * SCAN_PER;
    int s = 0;
#pragma unroll
    for (int k = 0; k < SCAN_PER; k += 4) {
        const int idx = base + k;
        if (idx + 3 < NCNT) {
            const int4 v = *reinterpret_cast<const int4*>(&c[idx]);
            s += v.x + v.y + v.z + v.w;
        } else {
            for (int q = 0; q < 4; ++q) if (idx + q < NCNT) s += c[idx + q];
        }
    }
    sm[t] = s;
    __syncthreads();
    for (int off = 128; off > 0; off >>= 1) {
        if (t < off) sm[t] += sm[t + off];
        __syncthreads();
    }
    if (t == 0) bsum[blockIdx.x] = sm[0];
}

// ---- CSR step 2b: exclusive scan of block sums (single block) ----
__global__ __launch_bounds__(512) void scan_bsum(int* __restrict__ bsum)
{
    __shared__ int sm[512];
    const int t = threadIdx.x;
    const int own = (t < SCAN_NBLK) ? bsum[t] : 0;
    sm[t] = own;
    __syncthreads();
    for (int off = 1; off < 512; off <<= 1) {
        int v = sm[t];
        if (t >= off) v += sm[t - off];
        __syncthreads();
        sm[t] = v;
        __syncthreads();
    }
    if (t < SCAN_NBLK) bsum[t] = sm[t] - own;   // exclusive
}

// ---- CSR step 2c: final exclusive scan -> row_ptr ----
__global__ __launch_bounds__(256) void scan_final(
    const int* __restrict__ c, const int* __restrict__ bsum,
    int* __restrict__ rp)
{
    __shared__ int sm[256];
    const int t = threadIdx.x;
    const int base = blockIdx.x * SCAN_CHUNK + t * SCAN_PER;
    int vals[SCAN_PER];
    int s = 0;
#pragma unroll
    for (int k = 0; k < SCAN_PER; k += 4) {
        const int idx = base + k;
        int4 v = make_int4(0, 0, 0, 0);
        if (idx + 3 < NCNT) {
            v = *reinterpret_cast<const int4*>(&c[idx]);
        } else {
            if (idx + 0 < NCNT) v.x = c[idx + 0];
            if (idx + 1 < NCNT) v.y = c[idx + 1];
            if (idx + 2 < NCNT) v.z = c[idx + 2];
            if (idx + 3 < NCNT) v.w = c[idx + 3];
        }
        vals[k + 0] = v.x; vals[k + 1] = v.y; vals[k + 2] = v.z; vals[k + 3] = v.w;
        s += v.x + v.y + v.z + v.w;
    }
    const int own = s;
    sm[t] = own;
    __syncthreads();
    for (int off = 1; off < 256; off <<= 1) {
        int v = sm[t];
        if (t >= off) v += sm[t - off];
        __syncthreads();
        sm[t] = v;
        __syncthreads();
    }
    int run = sm[t] - own + bsum[blockIdx.x];
#pragma unroll
    for (int k = 0; k < SCAN_PER; ++k) {
        if (base + k < NCNT) rp[base + k] = run;
        run += vals[k];
    }
    if (blockIdx.x == 0 && t == 0) rp[NCNT] = 4 * NEDGE;
}

// ---- CSR step 3: per-relation fill, ATOMIC-FREE via rank ----
__global__ __launch_bounds__(256) void fill_rel(
    const int* __restrict__ src, const int* __restrict__ dst,
    const int* __restrict__ rank, int base,
    const int* __restrict__ rp, int* __restrict__ eidx)
{
    const int e = blockIdx.x * 256 + threadIdx.x;
    if (e >= NEDGE) return;
    const int d = __builtin_nontemporal_load(dst + e);
    const int s = __builtin_nontemporal_load(src + e);
    const int r = __builtin_nontemporal_load(rank + e);
    eidx[rp[base + d] + r] = s;
}

// ---- pretransform v3: coalesced LDS staging + broadcast b128 weight reads.
__global__ __launch_bounds__(256) void pretransform_v3(
    const float* __restrict__ x,
    const float* __restrict__ WA, const float* __restrict__ WB,
    const float* __restrict__ WC1, const float* __restrict__ WC2,
    float* __restrict__ outA, float* __restrict__ outB, float* __restrict__ outC,
    int n)
{
    __shared__ float xs[256][33];                 // 32 cols + 1 pad
    __shared__ float wAs[1024], wBs[1024], wCs[1024];

    const int t = threadIdx.x;
    for (int i = t; i < 1024; i += 256) {
        wAs[i] = WA[i];
        wBs[i] = WB[i];
        wCs[i] = WC1[i] + WC2[i];
    }

    const int node0 = blockIdx.x * 256;
    const int nrow  = min(256, n - node0);

    float a[16], b[16], c[16];
#pragma unroll
    for (int i = 0; i < 16; ++i) { a[i] = 0.f; b[i] = 0.f; c[i] = 0.f; }

    for (int half = 0; half < 2; ++half) {
        __syncthreads();
#pragma unroll
        for (int it = 0; it < 8; ++it) {
            const int f = it * 1024 + t * 4;
            const int r = f >> 5, cc = f & 31;
            if (r < nrow) {
                const float4 v = *reinterpret_cast<const float4*>(
                    &x[(size_t)(node0 + r) * 64 + half * 32 + cc]);
                xs[r][cc + 0] = v.x;
                xs[r][cc + 1] = v.y;
                xs[r][cc + 2] = v.z;
                xs[r][cc + 3] = v.w;
            }
        }
        __syncthreads();

        if (t < nrow) {
            for (int kk = 0; kk < 32; ++kk) {
                const int k = half * 32 + kk;
                const float xv = xs[t][kk];
                const float4* wa4 = reinterpret_cast<const float4*>(&wAs[k * 16]);
                const float4* wb4 = reinterpret_cast<const float4*>(&wBs[k * 16]);
                const float4* wc4 = reinterpret_cast<const float4*>(&wCs[k * 16]);
#pragma unroll
                for (int q = 0; q < 4; ++q) {
                    const float4 wa = wa4[q], wb = wb4[q], wc = wc4[q];
                    a[q*4+0] = fmaf(xv, wa.x, a[q*4+0]);
                    a[q*4+1] = fmaf(xv, wa.y, a[q*4+1]);
                    a[q*4+2] = fmaf(xv, wa.z, a[q*4+2]);
                    a[q*4+3] = fmaf(xv, wa.w, a[q*4+3]);
                    b[q*4+0] = fmaf(xv, wb.x, b[q*4+0]);
                    b[q*4+1] = fmaf(xv, wb.y, b[q*4+1]);
                    b[q*4+2] = fmaf(xv, wb.z, b[q*4+2]);
                    b[q*4+3] = fmaf(xv, wb.w, b[q*4+3]);
                    c[q*4+0] = fmaf(xv, wc.x, c[q*4+0]);
                    c[q*4+1] = fmaf(xv, wc.y, c[q*4+1]);
                    c[q*4+2] = fmaf(xv, wc.z, c[q*4+2]);
                    c[q*4+3] = fmaf(xv, wc.w, c[q*4+3]);
                }
            }
        }
    }

    if (t < nrow) {
        const int node = node0 + t;
        float4* oA = reinterpret_cast<float4*>(&outA[(size_t)node * 16]);
        float4* oB = reinterpret_cast<float4*>(&outB[(size_t)node * 16]);
        float4* oC = reinterpret_cast<float4*>(&outC[(size_t)node * 16]);
#pragma unroll
        for (int i = 0; i < 4; ++i) {
            oA[i] = make_float4(a[i*4], a[i*4+1], a[i*4+2], a[i*4+3]);
            oB[i] = make_float4(b[i*4], b[i*4+1], b[i*4+2], b[i*4+3]);
            oC[i] = make_float4(c[i*4], c[i*4+1], c[i*4+2], c[i*4+3]);
        }
    }
}

// ---- 4-deep pipelined mean gather (16 lanes j=0..15 per node) ----
__device__ __forceinline__ float gather_mean16(
    const float* __restrict__ h, const int* __restrict__ eidx,
    int e0, int e1, int j)
{
    float acc = 0.f;
    int e = e0;
    for (; e + 4 <= e1; e += 4) {
        const int s0 = eidx[e + 0];
        const int s1 = eidx[e + 1];
        const int s2 = eidx[e + 2];
        const int s3 = eidx[e + 3];
        const float v0 = h[(size_t)s0 * 16 + j];
        const float v1 = h[(size_t)s1 * 16 + j];
        const float v2 = h[(size_t)s2 * 16 + j];
        const float v3 = h[(size_t)s3 * 16 + j];
        acc += (v0 + v1) + (v2 + v3);
    }
    if (e + 2 <= e1) {
        const int s0 = eidx[e + 0];
        const int s1 = eidx[e + 1];
        acc += h[(size_t)s0 * 16 + j] + h[(size_t)s1 * 16 + j];
        e += 2;
    }
    if (e < e1) acc += h[(size_t)eidx[e] * 16 + j];
    return acc * (1.f / fmaxf((float)(e1 - e0), 1.f));
}

// ---- L1 gather v2: 32 lanes/node (16 per relation, parallel chains) ----
__global__ __launch_bounds__(256) void gather_l1_v2(
    const float* __restrict__ hA, const float* __restrict__ hB,
    const int* __restrict__ rp, const int* __restrict__ eidx,
    int baseA, int baseB,
    const float* __restrict__ root,
    const float* __restrict__ bA, const float* __restrict__ bB,
    float* __restrict__ out, int n)
{
    const int t = threadIdx.x;
    const int sub = t & 31;          // lane within 32-group
    const int rel = sub >> 4;        // 0 = A, 1 = B
    const int j   = sub & 15;
    const int i   = blockIdx.x * 8 + (t >> 5);
    if (i >= n) return;

    // lanes {0,1} (rel0) and {16,17} (rel1) load this relation's rp pair
    int v = 0;
    if (j < 2) v = rp[(rel ? baseB : baseA) + i + j];
    const int e0 = __shfl(v, rel * 16 + 0, 32);
    const int e1 = __shfl(v, rel * 16 + 1, 32);

    const float* h = rel ? hB : hA;
    const float m = gather_mean16(h, eidx, e0, e1, j);
    const float sum = m + __shfl_xor(m, 16, 32);   // mA + mB in both halves

    if (rel == 0) {
        const float r = sum + root[(size_t)i * 16 + j] + bA[j] + bB[j];
        out[(size_t)i * 16 + j] = fmaxf(r, 0.f);
    }
}

// ---- L2 gather v2 + 16->32 matmul. 8 nodes/block, 32 lanes/node ----
__global__ __launch_bounds__(256) void gather_l2_v2(
    const float* __restrict__ hA, const float* __restrict__ hB,
    const int* __restrict__ rp, const int* __restrict__ eidx,
    int baseA, int baseB,
    const float* __restrict__ xroot,
    const float* __restrict__ WA, const float* __restrict__ WB,
    const float* __restrict__ WR1, const float* __restrict__ WR2,
    const float* __restrict__ bA, const float* __restrict__ bB,
    float* __restrict__ out, int n)
{
    __shared__ float wA[512], wB[512], wR[512], bs[32];
    __shared__ float smA[8][17], smB[8][17], smR[8][17];

    const int t = threadIdx.x;
    for (int i = t; i < 512; i += 256) {
        wA[i] = WA[i];
        wB[i] = WB[i];
        wR[i] = WR1[i] + WR2[i];
    }
    if (t < 32) bs[t] = bA[t] + bB[t];

    const int sub = t & 31;
    const int rel = sub >> 4;
    const int j   = sub & 15;
    const int g   = t >> 5;                  // node slot 0..7
    const int i   = blockIdx.x * 8 + g;

    if (i < n) {
        int v = 0;
        if (j < 2) v = rp[(rel ? baseB : baseA) + i + j];
        const int e0 = __shfl(v, rel * 16 + 0, 32);
        const int e1 = __shfl(v, rel * 16 + 1, 32);
        const float* h = rel ? hB : hA;
        const float m = gather_mean16(h, eidx, e0, e1, j);
        if (rel == 0) {
            smA[g][j] = m;
            smR[g][j] = xroot[(size_t)i * 16 + j];
        } else {
            smB[g][j] = m;
        }
    }
    __syncthreads();

    // matmul phase: node g2 = t>>5, col = t&31, one output per thread
    const int g2  = t >> 5;
    const int col = t & 31;
    const int i2  = blockIdx.x * 8 + g2;
    if (i2 >= n) return;
    float acc = bs[col];
#pragma unroll
    for (int k = 0; k < 16; ++k) {
        acc = fmaf(smA[g2][k], wA[k * 32 + col], acc);
        acc = fmaf(smB[g2][k], wB[k * 32 + col], acc);
        acc = fmaf(smR[g2][k], wR[k * 32 + col], acc);
    }
    out[(size_t)i2 * 32 + col] = acc;
}

extern "C" void kernel_launch(void* const* d_in, const int* in_sizes, int n_in,
                              void* d_out, int out_size, void* d_ws, size_t ws_size,
                              hipStream_t stream)
{
    const float* x_dev  = (const float*)d_in[0];
    const float* x_task = (const float*)d_in[1];
    const int* wr_src = (const int*)d_in[2];
    const int* wr_dst = (const int*)d_in[3];
    const int* rv_src = (const int*)d_in[4];
    const int* rv_dst = (const int*)d_in[5];
    const int* wb_src = (const int*)d_in[6];
    const int* wb_dst = (const int*)d_in[7];
    const int* rb_src = (const int*)d_in[8];
    const int* rb_dst = (const int*)d_in[9];
    const float* p1wr_wl = (const float*)d_in[10];
    const float* p1wr_bl = (const float*)d_in[11];
    const float* p1wr_wr = (const float*)d_in[12];
    const float* p1rv_wl = (const float*)d_in[13];
    const float* p1rv_bl = (const float*)d_in[14];
    const float* p1rv_wr = (const float*)d_in[15];
    const float* p1wb_wl = (const float*)d_in[16];
    const float* p1wb_bl = (const float*)d_in[17];
    const float* p1wb_wr = (const float*)d_in[18];
    const float* p1rb_wl = (const float*)d_in[19];
    const float* p1rb_bl = (const float*)d_in[20];
    const float* p1rb_wr = (const float*)d_in[21];
    const float* p2wr_wl = (const float*)d_in[22];
    const float* p2wr_bl = (const float*)d_in[23];
    const float* p2wr_wr = (const float*)d_in[24];
    const float* p2rv_wl = (const float*)d_in[25];
    const float* p2rv_bl = (const float*)d_in[26];
    const float* p2rv_wr = (const float*)d_in[27];
    const float* p2wb_wl = (const float*)d_in[28];
    const float* p2wb_bl = (const float*)d_in[29];
    const float* p2wb_wr = (const float*)d_in[30];
    const float* p2rb_wl = (const float*)d_in[31];
    const float* p2rb_bl = (const float*)d_in[32];
    const float* p2rb_wr = (const float*)d_in[33];

    // ---- workspace carve-up ----
    int* wsI = (int*)d_ws;
    int* cnt  = wsI + 0;            // 1.2M
    int* rp   = wsI + 1200000;      // 1.2M + 1
    int* rank = wsI + 2400004;      // 4M (per-edge rank, 4 relations)
    int* eidx = wsI + 6400004;      // 4M
    int* bsum = wsI + 10400004;     // 512
    float* wsF = (float*)d_ws + 10400768;   // 16B-aligned float region
    float* h_wr   = wsF + 0;         // dev  x16
    float* h_rv   = wsF + 1600000;   // dev  x16
    float* h_wb   = wsF + 3200000;   // task x16
    float* h_rb   = wsF + 11200000;  // task x16
    float* root_d = wsF + 19200000;  // dev  x16
    float* root_t = wsF + 20800000;  // task x16
    float* t1     = wsF + 28800000;  // task x16
    float* d1     = wsF + 36800000;  // dev  x16

    float* out = (float*)d_out;      // [d2: 100K x32 | t2: 500K x32]

    const int eblk = (NEDGE + 255) / 256;

    // ---- 1. CSR build (rank trick: fills are atomic-free) ----
    hipMemsetAsync(cnt, 0, (size_t)NCNT * sizeof(int), stream);
    hist_rank_rel<<<eblk, 256, 0, stream>>>(wr_dst, BASE_WR, cnt, rank + 0 * NEDGE);
    hist_rank_rel<<<eblk, 256, 0, stream>>>(rv_dst, BASE_RV, cnt, rank + 1 * NEDGE);
    hist_rank_rel<<<eblk, 256, 0, stream>>>(wb_dst, BASE_WB, cnt, rank + 2 * NEDGE);
    hist_rank_rel<<<eblk, 256, 0, stream>>>(rb_dst, BASE_RB, cnt, rank + 3 * NEDGE);
    scan_block_sums<<<SCAN_NBLK, 256, 0, stream>>>(cnt, bsum);
    scan_bsum<<<1, 512, 0, stream>>>(bsum);
    scan_final<<<SCAN_NBLK, 256, 0, stream>>>(cnt, bsum, rp);
    fill_rel<<<eblk, 256, 0, stream>>>(wr_src, wr_dst, rank + 0 * NEDGE, BASE_WR, rp, eidx);
    fill_rel<<<eblk, 256, 0, stream>>>(rv_src, rv_dst, rank + 1 * NEDGE, BASE_RV, rp, eidx);
    fill_rel<<<eblk, 256, 0, stream>>>(wb_src, wb_dst, rank + 2 * NEDGE, BASE_WB, rp, eidx);
    fill_rel<<<eblk, 256, 0, stream>>>(rb_src, rb_dst, rank + 3 * NEDGE, BASE_RB, rp, eidx);

    // ---- 2. pretransforms (h_rel + summed-root) ----
    pretransform_v3<<<(N_DEV + 255) / 256, 256, 0, stream>>>(
        x_dev, p1wr_wl, p1rv_wl, p1wb_wr, p1rb_wr, h_wr, h_rv, root_d, N_DEV);
    pretransform_v3<<<(N_TASK + 255) / 256, 256, 0, stream>>>(
        x_task, p1wb_wl, p1rb_wl, p1wr_wr, p1rv_wr, h_wb, h_rb, root_t, N_TASK);

    // ---- 3. L1 fused gathers ----
    gather_l1_v2<<<(N_TASK + 7) / 8, 256, 0, stream>>>(
        h_wr, h_rv, rp, eidx, BASE_WR, BASE_RV, root_t, p1wr_bl, p1rv_bl, t1, N_TASK);
    gather_l1_v2<<<(N_DEV + 7) / 8, 256, 0, stream>>>(
        h_wb, h_rb, rp, eidx, BASE_WB, BASE_RB, root_d, p1wb_bl, p1rb_bl, d1, N_DEV);

    // ---- 4. L2 fused gather + matmul -> d_out ----
    gather_l2_v2<<<(N_TASK + 7) / 8, 256, 0, stream>>>(
        d1, d1, rp, eidx, BASE_WR, BASE_RV, t1,
        p2wr_wl, p2rv_wl, p2wr_wr, p2rv_wr, p2wr_bl, p2rv_bl,
        out + (size_t)N_DEV * 32, N_TASK);
    gather_l2_v2<<<(N_DEV + 7) / 8, 256, 0, stream>>>(
        t1, t1, rp, eidx, BASE_WB, BASE_RB, d1,
        p2wb_wl, p2rb_wl, p2wb_wr, p2rb_wr, p2wb_bl, p2rb_bl,
        out, N_DEV);
}

// Round 8
// 914.796 us; speedup vs baseline: 1.3197x; 1.0829x over previous
//
#include <hip/hip_runtime.h>

// ---------------------------------------------------------------------------
// Hetero 2-layer GraphSAGE — CSR-gather, round 8.
//
// Round-7 lesson (rocprof): gather_l2_v2 is VALU-ISSUE-bound (VALUBusy 62%,
// occ 84%, VGPR 16, FETCH 116 MB fully L3-absorbed). ~480 wave-inst/thread,
// 3x the essential work: 64-bit index chains, divergent rel branches, and a
// matmul epilogue costing 144 inst per output. This round: instruction diet.
//   * gather_l2_v3: 32 nodes/block; 8 lanes/node gather (dims j, j+8);
//     matmul = 4 cols/thread via float4 W reads + float4 store
//     (72 inst/output, 2x cut); 4x fewer weight-staging blocks.
//   * all gathers: 32-bit unsigned indexing (saddr-form loads), plain
//     broadcast rp loads (no shfl dedup), lean 2-wide edge loop.
//   * CSR build + pretransform untouched (clean A/B on the gather diet).
// ---------------------------------------------------------------------------

#define N_DEV   100000
#define N_TASK  500000
#define NEDGE   1000000
#define NCNT    1200000          // 500K (wr) + 500K (rv) + 100K (wb) + 100K (rb)
#define BASE_WR 0
#define BASE_RV 500000
#define BASE_WB 1000000
#define BASE_RB 1100000

#define SCAN_PER   16
#define SCAN_CHUNK 4096          // 256 threads * 16
#define SCAN_NBLK  293           // ceil(1.2M / 4096)

// ---- CSR step 1: per-relation histogram + per-edge rank capture ----
__global__ __launch_bounds__(256) void hist_rank_rel(
    const int* __restrict__ dst, int base,
    int* __restrict__ cnt, int* __restrict__ rank)
{
    const int e = blockIdx.x * 256 + threadIdx.x;
    if (e >= NEDGE) return;
    const int d = __builtin_nontemporal_load(dst + e);
    rank[e] = atomicAdd(&cnt[base + d], 1);
}

// ---- CSR step 2a: per-block sums of counters ----
__global__ __launch_bounds__(256) void scan_block_sums(
    const int* __restrict__ c, int* __restrict__ bsum)
{
    __shared__ int sm[256];
    const int t = threadIdx.x;
    const int base = blockIdx.x * SCAN_CHUNK + t * SCAN_PER;
    int s = 0;
#pragma unroll
    for (int k = 0; k < SCAN_PER; k += 4) {
        const int idx = base + k;
        if (idx + 3 < NCNT) {
            const int4 v = *reinterpret_cast<const int4*>(&c[idx]);
            s += v.x + v.y + v.z + v.w;
        } else {
            for (int q = 0; q < 4; ++q) if (idx + q < NCNT) s += c[idx + q];
        }
    }
    sm[t] = s;
    __syncthreads();
    for (int off = 128; off > 0; off >>= 1) {
        if (t < off) sm[t] += sm[t + off];
        __syncthreads();
    }
    if (t == 0) bsum[blockIdx.x] = sm[0];
}

// ---- CSR step 2b: exclusive scan of block sums (single block) ----
__global__ __launch_bounds__(512) void scan_bsum(int* __restrict__ bsum)
{
    __shared__ int sm[512];
    const int t = threadIdx.x;
    const int own = (t < SCAN_NBLK) ? bsum[t] : 0;
    sm[t] = own;
    __syncthreads();
    for (int off = 1; off < 512; off <<= 1) {
        int v = sm[t];
        if (t >= off) v += sm[t - off];
        __syncthreads();
        sm[t] = v;
        __syncthreads();
    }
    if (t < SCAN_NBLK) bsum[t] = sm[t] - own;   // exclusive
}

// ---- CSR step 2c: final exclusive scan -> row_ptr ----
__global__ __launch_bounds__(256) void scan_final(
    const int* __restrict__ c, const int* __restrict__ bsum,
    int* __restrict__ rp)
{
    __shared__ int sm[256];
    const int t = threadIdx.x;
    const int base = blockIdx.x * SCAN_CHUNK + t * SCAN_PER;
    int vals[SCAN_PER];
    int s = 0;
#pragma unroll
    for (int k = 0; k < SCAN_PER; k += 4) {
        const int idx = base + k;
        int4 v = make_int4(0, 0, 0, 0);
        if (idx + 3 < NCNT) {
            v = *reinterpret_cast<const int4*>(&c[idx]);
        } else {
            if (idx + 0 < NCNT) v.x = c[idx + 0];
            if (idx + 1 < NCNT) v.y = c[idx + 1];
            if (idx + 2 < NCNT) v.z = c[idx + 2];
            if (idx + 3 < NCNT) v.w = c[idx + 3];
        }
        vals[k + 0] = v.x; vals[k + 1] = v.y; vals[k + 2] = v.z; vals[k + 3] = v.w;
        s += v.x + v.y + v.z + v.w;
    }
    const int own = s;
    sm[t] = own;
    __syncthreads();
    for (int off = 1; off < 256; off <<= 1) {
        int v = sm[t];
        if (t >= off) v += sm[t - off];
        __syncthreads();
        sm[t] = v;
        __syncthreads();
    }
    int run = sm[t] - own + bsum[blockIdx.x];
#pragma unroll
    for (int k = 0; k < SCAN_PER; ++k) {
        if (base + k < NCNT) rp[base + k] = run;
        run += vals[k];
    }
    if (blockIdx.x == 0 && t == 0) rp[NCNT] = 4 * NEDGE;
}

// ---- CSR step 3: per-relation fill, atomic-free via rank ----
__global__ __launch_bounds__(256) void fill_rel(
    const int* __restrict__ src, const int* __restrict__ dst,
    const int* __restrict__ rank, int base,
    const int* __restrict__ rp, int* __restrict__ eidx)
{
    const int e = blockIdx.x * 256 + threadIdx.x;
    if (e >= NEDGE) return;
    const int d = __builtin_nontemporal_load(dst + e);
    const int s = __builtin_nontemporal_load(src + e);
    const int r = __builtin_nontemporal_load(rank + e);
    eidx[rp[base + d] + r] = s;
}

// ---- pretransform v3: coalesced LDS staging + broadcast b128 weight reads.
__global__ __launch_bounds__(256) void pretransform_v3(
    const float* __restrict__ x,
    const float* __restrict__ WA, const float* __restrict__ WB,
    const float* __restrict__ WC1, const float* __restrict__ WC2,
    float* __restrict__ outA, float* __restrict__ outB, float* __restrict__ outC,
    int n)
{
    __shared__ float xs[256][33];                 // 32 cols + 1 pad
    __shared__ float wAs[1024], wBs[1024], wCs[1024];

    const int t = threadIdx.x;
    for (int i = t; i < 1024; i += 256) {
        wAs[i] = WA[i];
        wBs[i] = WB[i];
        wCs[i] = WC1[i] + WC2[i];
    }

    const int node0 = blockIdx.x * 256;
    const int nrow  = min(256, n - node0);

    float a[16], b[16], c[16];
#pragma unroll
    for (int i = 0; i < 16; ++i) { a[i] = 0.f; b[i] = 0.f; c[i] = 0.f; }

    for (int half = 0; half < 2; ++half) {
        __syncthreads();
#pragma unroll
        for (int it = 0; it < 8; ++it) {
            const int f = it * 1024 + t * 4;
            const int r = f >> 5, cc = f & 31;
            if (r < nrow) {
                const float4 v = *reinterpret_cast<const float4*>(
                    &x[(size_t)(node0 + r) * 64 + half * 32 + cc]);
                xs[r][cc + 0] = v.x;
                xs[r][cc + 1] = v.y;
                xs[r][cc + 2] = v.z;
                xs[r][cc + 3] = v.w;
            }
        }
        __syncthreads();

        if (t < nrow) {
            for (int kk = 0; kk < 32; ++kk) {
                const int k = half * 32 + kk;
                const float xv = xs[t][kk];
                const float4* wa4 = reinterpret_cast<const float4*>(&wAs[k * 16]);
                const float4* wb4 = reinterpret_cast<const float4*>(&wBs[k * 16]);
                const float4* wc4 = reinterpret_cast<const float4*>(&wCs[k * 16]);
#pragma unroll
                for (int q = 0; q < 4; ++q) {
                    const float4 wa = wa4[q], wb = wb4[q], wc = wc4[q];
                    a[q*4+0] = fmaf(xv, wa.x, a[q*4+0]);
                    a[q*4+1] = fmaf(xv, wa.y, a[q*4+1]);
                    a[q*4+2] = fmaf(xv, wa.z, a[q*4+2]);
                    a[q*4+3] = fmaf(xv, wa.w, a[q*4+3]);
                    b[q*4+0] = fmaf(xv, wb.x, b[q*4+0]);
                    b[q*4+1] = fmaf(xv, wb.y, b[q*4+1]);
                    b[q*4+2] = fmaf(xv, wb.z, b[q*4+2]);
                    b[q*4+3] = fmaf(xv, wb.w, b[q*4+3]);
                    c[q*4+0] = fmaf(xv, wc.x, c[q*4+0]);
                    c[q*4+1] = fmaf(xv, wc.y, c[q*4+1]);
                    c[q*4+2] = fmaf(xv, wc.z, c[q*4+2]);
                    c[q*4+3] = fmaf(xv, wc.w, c[q*4+3]);
                }
            }
        }
    }

    if (t < nrow) {
        const int node = node0 + t;
        float4* oA = reinterpret_cast<float4*>(&outA[(size_t)node * 16]);
        float4* oB = reinterpret_cast<float4*>(&outB[(size_t)node * 16]);
        float4* oC = reinterpret_cast<float4*>(&outC[(size_t)node * 16]);
#pragma unroll
        for (int i = 0; i < 4; ++i) {
            oA[i] = make_float4(a[i*4], a[i*4+1], a[i*4+2], a[i*4+3]);
            oB[i] = make_float4(b[i*4], b[i*4+1], b[i*4+2], b[i*4+3]);
            oC[i] = make_float4(c[i*4], c[i*4+1], c[i*4+2], c[i*4+3]);
        }
    }
}

// ---- lean mean gather: one feature dim j per call site, uint addressing ----
__device__ __forceinline__ float gather_mean_j(
    const float* __restrict__ h, const int* __restrict__ eidx,
    int e0, int e1, int j)
{
    float acc = 0.f;
    int e = e0;
    for (; e + 2 <= e1; e += 2) {
        const unsigned s0 = (unsigned)eidx[e] << 4;
        const unsigned s1 = (unsigned)eidx[e + 1] << 4;
        acc += h[s0 + j] + h[s1 + j];
    }
    if (e < e1) acc += h[((unsigned)eidx[e] << 4) + j];
    return acc * (1.f / fmaxf((float)(e1 - e0), 1.f));
}

// ---- L1 gather v3: 32 lanes/node (16 per relation), diet addressing ----
__global__ __launch_bounds__(256) void gather_l1_v3(
    const float* __restrict__ hA, const float* __restrict__ hB,
    const int* __restrict__ rp, const int* __restrict__ eidx,
    int baseA, int baseB,
    const float* __restrict__ root,
    const float* __restrict__ bA, const float* __restrict__ bB,
    float* __restrict__ out, int n)
{
    const int t = threadIdx.x;
    const int sub = t & 31;          // lane within 32-group
    const int rel = sub >> 4;        // 0 = A, 1 = B
    const int j   = sub & 15;
    const int i   = blockIdx.x * 8 + (t >> 5);
    if (i >= n) return;

    const int b = rel ? baseB : baseA;
    const int e0 = rp[b + i];
    const int e1 = rp[b + i + 1];
    const float* h = rel ? hB : hA;

    float m = gather_mean_j(h, eidx, e0, e1, j);
    m += __shfl_xor(m, 16, 32);      // mA + mB in both halves

    if (rel == 0) {
        const unsigned o = ((unsigned)i << 4) + j;
        out[o] = fmaxf(m + root[o] + bA[j] + bB[j], 0.f);
    }
}

// ---- L2 gather v3 + 16->32 matmul. 32 nodes/block, 8 lanes/node gather,
//      4 cols/thread matmul (float4 W reads, float4 store). ----
__global__ __launch_bounds__(256) void gather_l2_v3(
    const float* __restrict__ hA, const float* __restrict__ hB,
    const int* __restrict__ rp, const int* __restrict__ eidx,
    int baseA, int baseB,
    const float* __restrict__ xroot,
    const float* __restrict__ WA, const float* __restrict__ WB,
    const float* __restrict__ WR1, const float* __restrict__ WR2,
    const float* __restrict__ bA, const float* __restrict__ bB,
    float* __restrict__ out, int n)
{
    __shared__ float wA[512], wB[512], wR[512], bs[32];
    __shared__ float smA[32][17], smB[32][17], smR[32][17];

    const int t = threadIdx.x;
    for (int q = t; q < 512; q += 256) {
        wA[q] = WA[q];
        wB[q] = WB[q];
        wR[q] = WR1[q] + WR2[q];
    }
    if (t < 32) bs[t] = bA[t] + bB[t];

    const int g = t >> 3;            // node slot 0..31
    const int j = t & 7;             // covers dims j and j+8
    const int i = blockIdx.x * 32 + g;

    if (i < n) {
        // relation A
        {
            const int e0 = rp[baseA + i], e1 = rp[baseA + i + 1];
            float m0 = 0.f, m1 = 0.f;
            int e = e0;
            for (; e + 2 <= e1; e += 2) {
                const unsigned s0 = (unsigned)eidx[e] << 4;
                const unsigned s1 = (unsigned)eidx[e + 1] << 4;
                m0 += hA[s0 + j]     + hA[s1 + j];
                m1 += hA[s0 + j + 8] + hA[s1 + j + 8];
            }
            if (e < e1) {
                const unsigned s = (unsigned)eidx[e] << 4;
                m0 += hA[s + j];
                m1 += hA[s + j + 8];
            }
            const float inv = 1.f / fmaxf((float)(e1 - e0), 1.f);
            smA[g][j]     = m0 * inv;
            smA[g][j + 8] = m1 * inv;
        }
        // relation B
        {
            const int e0 = rp[baseB + i], e1 = rp[baseB + i + 1];
            float m0 = 0.f, m1 = 0.f;
            int e = e0;
            for (; e + 2 <= e1; e += 2) {
                const unsigned s0 = (unsigned)eidx[e] << 4;
                const unsigned s1 = (unsigned)eidx[e + 1] << 4;
                m0 += hB[s0 + j]     + hB[s1 + j];
                m1 += hB[s0 + j + 8] + hB[s1 + j + 8];
            }
            if (e < e1) {
                const unsigned s = (unsigned)eidx[e] << 4;
                m0 += hB[s + j];
                m1 += hB[s + j + 8];
            }
            const float inv = 1.f / fmaxf((float)(e1 - e0), 1.f);
            smB[g][j]     = m0 * inv;
            smB[g][j + 8] = m1 * inv;
        }
        // root
        const unsigned ri = ((unsigned)i << 4) + j;
        smR[g][j]     = xroot[ri];
        smR[g][j + 8] = xroot[ri + 8];
    }
    __syncthreads();

    // matmul phase: node g2 = t>>3, cols [4p, 4p+3], one float4 per thread
    const int g2 = t >> 3;
    const int p  = t & 7;
    const int i2 = blockIdx.x * 32 + g2;
    if (i2 >= n) return;
    const int c0 = p * 4;
    float4 acc = *reinterpret_cast<const float4*>(&bs[c0]);
#pragma unroll
    for (int k = 0; k < 16; ++k) {
        const float a = smA[g2][k], b = smB[g2][k], r = smR[g2][k];
        const float4 wa = *reinterpret_cast<const float4*>(&wA[k * 32 + c0]);
        const float4 wb = *reinterpret_cast<const float4*>(&wB[k * 32 + c0]);
        const float4 wr = *reinterpret_cast<const float4*>(&wR[k * 32 + c0]);
        acc.x = fmaf(a, wa.x, acc.x);
        acc.x = fmaf(b, wb.x, acc.x);
        acc.x = fmaf(r, wr.x, acc.x);
        acc.y = fmaf(a, wa.y, acc.y);
        acc.y = fmaf(b, wb.y, acc.y);
        acc.y = fmaf(r, wr.y, acc.y);
        acc.z = fmaf(a, wa.z, acc.z);
        acc.z = fmaf(b, wb.z, acc.z);
        acc.z = fmaf(r, wr.z, acc.z);
        acc.w = fmaf(a, wa.w, acc.w);
        acc.w = fmaf(b, wb.w, acc.w);
        acc.w = fmaf(r, wr.w, acc.w);
    }
    *reinterpret_cast<float4*>(&out[(size_t)i2 * 32 + c0]) = acc;
}

extern "C" void kernel_launch(void* const* d_in, const int* in_sizes, int n_in,
                              void* d_out, int out_size, void* d_ws, size_t ws_size,
                              hipStream_t stream)
{
    const float* x_dev  = (const float*)d_in[0];
    const float* x_task = (const float*)d_in[1];
    const int* wr_src = (const int*)d_in[2];
    const int* wr_dst = (const int*)d_in[3];
    const int* rv_src = (const int*)d_in[4];
    const int* rv_dst = (const int*)d_in[5];
    const int* wb_src = (const int*)d_in[6];
    const int* wb_dst = (const int*)d_in[7];
    const int* rb_src = (const int*)d_in[8];
    const int* rb_dst = (const int*)d_in[9];
    const float* p1wr_wl = (const float*)d_in[10];
    const float* p1wr_bl = (const float*)d_in[11];
    const float* p1wr_wr = (const float*)d_in[12];
    const float* p1rv_wl = (const float*)d_in[13];
    const float* p1rv_bl = (const float*)d_in[14];
    const float* p1rv_wr = (const float*)d_in[15];
    const float* p1wb_wl = (const float*)d_in[16];
    const float* p1wb_bl = (const float*)d_in[17];
    const float* p1wb_wr = (const float*)d_in[18];
    const float* p1rb_wl = (const float*)d_in[19];
    const float* p1rb_bl = (const float*)d_in[20];
    const float* p1rb_wr = (const float*)d_in[21];
    const float* p2wr_wl = (const float*)d_in[22];
    const float* p2wr_bl = (const float*)d_in[23];
    const float* p2wr_wr = (const float*)d_in[24];
    const float* p2rv_wl = (const float*)d_in[25];
    const float* p2rv_bl = (const float*)d_in[26];
    const float* p2rv_wr = (const float*)d_in[27];
    const float* p2wb_wl = (const float*)d_in[28];
    const float* p2wb_bl = (const float*)d_in[29];
    const float* p2wb_wr = (const float*)d_in[30];
    const float* p2rb_wl = (const float*)d_in[31];
    const float* p2rb_bl = (const float*)d_in[32];
    const float* p2rb_wr = (const float*)d_in[33];

    // ---- workspace carve-up ----
    int* wsI = (int*)d_ws;
    int* cnt  = wsI + 0;            // 1.2M
    int* rp   = wsI + 1200000;      // 1.2M + 1
    int* rank = wsI + 2400004;      // 4M (per-edge rank, 4 relations)
    int* eidx = wsI + 6400004;      // 4M
    int* bsum = wsI + 10400004;     // 512
    float* wsF = (float*)d_ws + 10400768;   // 16B-aligned float region
    float* h_wr   = wsF + 0;         // dev  x16
    float* h_rv   = wsF + 1600000;   // dev  x16
    float* h_wb   = wsF + 3200000;   // task x16
    float* h_rb   = wsF + 11200000;  // task x16
    float* root_d = wsF + 19200000;  // dev  x16
    float* root_t = wsF + 20800000;  // task x16
    float* t1     = wsF + 28800000;  // task x16
    float* d1     = wsF + 36800000;  // dev  x16

    float* out = (float*)d_out;      // [d2: 100K x32 | t2: 500K x32]

    const int eblk = (NEDGE + 255) / 256;

    // ---- 1. CSR build (rank trick: fills are atomic-free) ----
    hipMemsetAsync(cnt, 0, (size_t)NCNT * sizeof(int), stream);
    hist_rank_rel<<<eblk, 256, 0, stream>>>(wr_dst, BASE_WR, cnt, rank + 0 * NEDGE);
    hist_rank_rel<<<eblk, 256, 0, stream>>>(rv_dst, BASE_RV, cnt, rank + 1 * NEDGE);
    hist_rank_rel<<<eblk, 256, 0, stream>>>(wb_dst, BASE_WB, cnt, rank + 2 * NEDGE);
    hist_rank_rel<<<eblk, 256, 0, stream>>>(rb_dst, BASE_RB, cnt, rank + 3 * NEDGE);
    scan_block_sums<<<SCAN_NBLK, 256, 0, stream>>>(cnt, bsum);
    scan_bsum<<<1, 512, 0, stream>>>(bsum);
    scan_final<<<SCAN_NBLK, 256, 0, stream>>>(cnt, bsum, rp);
    fill_rel<<<eblk, 256, 0, stream>>>(wr_src, wr_dst, rank + 0 * NEDGE, BASE_WR, rp, eidx);
    fill_rel<<<eblk, 256, 0, stream>>>(rv_src, rv_dst, rank + 1 * NEDGE, BASE_RV, rp, eidx);
    fill_rel<<<eblk, 256, 0, stream>>>(wb_src, wb_dst, rank + 2 * NEDGE, BASE_WB, rp, eidx);
    fill_rel<<<eblk, 256, 0, stream>>>(rb_src, rb_dst, rank + 3 * NEDGE, BASE_RB, rp, eidx);

    // ---- 2. pretransforms (h_rel + summed-root) ----
    pretransform_v3<<<(N_DEV + 255) / 256, 256, 0, stream>>>(
        x_dev, p1wr_wl, p1rv_wl, p1wb_wr, p1rb_wr, h_wr, h_rv, root_d, N_DEV);
    pretransform_v3<<<(N_TASK + 255) / 256, 256, 0, stream>>>(
        x_task, p1wb_wl, p1rb_wl, p1wr_wr, p1rv_wr, h_wb, h_rb, root_t, N_TASK);

    // ---- 3. L1 fused gathers ----
    gather_l1_v3<<<(N_TASK + 7) / 8, 256, 0, stream>>>(
        h_wr, h_rv, rp, eidx, BASE_WR, BASE_RV, root_t, p1wr_bl, p1rv_bl, t1, N_TASK);
    gather_l1_v3<<<(N_DEV + 7) / 8, 256, 0, stream>>>(
        h_wb, h_rb, rp, eidx, BASE_WB, BASE_RB, root_d, p1wb_bl, p1rb_bl, d1, N_DEV);

    // ---- 4. L2 fused gather + matmul -> d_out ----
    gather_l2_v3<<<(N_TASK + 31) / 32, 256, 0, stream>>>(
        d1, d1, rp, eidx, BASE_WR, BASE_RV, t1,
        p2wr_wl, p2rv_wl, p2wr_wr, p2rv_wr, p2wr_bl, p2rv_bl,
        out + (size_t)N_DEV * 32, N_TASK);
    gather_l2_v3<<<(N_DEV + 31) / 32, 256, 0, stream>>>(
        t1, t1, rp, eidx, BASE_WB, BASE_RB, d1,
        p2wb_wl, p2rb_wl, p2wb_wr, p2rb_wr, p2wb_bl, p2rb_bl,
        out, N_DEV);
}